// Round 1
// baseline (1198.850 us; speedup 1.0000x reference)
//
#include <hip/hip_runtime.h>
#include <hip/hip_bf16.h>
#include <math.h>

// ---------------------------------------------------------------------------
// RGAT (2 relations) x2 + BatchNorm + head, fp32.
// Pipeline:
//   1. CSR-by-dst (hist -> scan -> scatter)
//   2. xw[r] = x @ W[r]            (tiled fp32 GEMM, 64x64 tile)
//   3. a_i = xw . q, a_j = xw . k  (wave per (r,node))
//   4. per-dst-node aggregation: online segment softmax + weighted sum
//   5. BN (double-atomic stats, fused scale/shift apply)
//   6. repeat for layer 1, then gather idx rows + sigmoid head
// ---------------------------------------------------------------------------

#define WAVE 64

// ---------------- CSR build ----------------
__global__ __launch_bounds__(256) void k_hist(const int* __restrict__ dst,
                                              int* __restrict__ deg, int E) {
  int e = blockIdx.x * blockDim.x + threadIdx.x;
  if (e < E) atomicAdd(&deg[dst[e]], 1);
}

__global__ __launch_bounds__(256) void k_scan(const int* __restrict__ deg,
                                              int* __restrict__ rowptr, int n) {
  __shared__ int lsum[256];
  int t = threadIdx.x;
  int chunk = (n + 255) >> 8;
  int s0 = t * chunk;
  int s1 = s0 + chunk; if (s1 > n) s1 = n; if (s0 > n) s0 = n;
  int acc = 0;
  for (int i = s0; i < s1; ++i) acc += deg[i];
  lsum[t] = acc;
  __syncthreads();
  for (int o = 1; o < 256; o <<= 1) {
    int v = 0;
    if (t >= o) v = lsum[t - o];
    __syncthreads();
    if (t >= o) lsum[t] += v;
    __syncthreads();
  }
  int run = (t > 0) ? lsum[t - 1] : 0;
  for (int i = s0; i < s1; ++i) { rowptr[i] = run; run += deg[i]; }
  if (t == 255) rowptr[n] = lsum[255];
}

__global__ __launch_bounds__(256) void k_copy_int(const int* __restrict__ a,
                                                  int* __restrict__ b, int n) {
  int i = blockIdx.x * blockDim.x + threadIdx.x;
  if (i < n) b[i] = a[i];
}

__global__ __launch_bounds__(256) void k_scatter(const int* __restrict__ dst,
                                                 int* __restrict__ cursor,
                                                 int* __restrict__ csr, int E) {
  int e = blockIdx.x * blockDim.x + threadIdx.x;
  if (e < E) {
    int p = atomicAdd(&cursor[dst[e]], 1);
    csr[p] = e;
  }
}

// ---------------- fp32 GEMM: C[r] = A @ B[r] ----------------
// A:[M,K] rowmajor, B:[R,K,Nc], C:[R,M,Nc]. Nc%64==0, K%32==0.
__global__ __launch_bounds__(256) void k_gemm(const float* __restrict__ A,
                                              const float* __restrict__ B,
                                              float* __restrict__ C,
                                              int M, int K, int Nc) {
  const int r  = blockIdx.z;
  const int m0 = blockIdx.y * 64;
  const int n0 = blockIdx.x * 64;
  const float* Br = B + (size_t)r * K * Nc;
  float* Cr = C + (size_t)r * M * Nc;
  __shared__ float As[32][65];
  __shared__ float Bs[32][64];
  const int tid = threadIdx.x;
  const int tx = tid & 15, ty = tid >> 4;
  float acc[4][4] = {};
  for (int kk0 = 0; kk0 < K; kk0 += 32) {
    // stage A tile (64 rows x 32 k), transposed into As[k][m]
#pragma unroll
    for (int it = 0; it < 2; ++it) {
      int row = (tid >> 3) + it * 32;
      int kk  = (tid & 7) * 4;
      int gm  = m0 + row;
      float4 v = make_float4(0.f, 0.f, 0.f, 0.f);
      if (gm < M) v = *(const float4*)&A[(size_t)gm * K + kk0 + kk];
      As[kk + 0][row] = v.x; As[kk + 1][row] = v.y;
      As[kk + 2][row] = v.z; As[kk + 3][row] = v.w;
    }
    // stage B tile (32 k x 64 n)
#pragma unroll
    for (int it = 0; it < 2; ++it) {
      int row = (tid >> 4) + it * 16;
      int nn  = (tid & 15) * 4;
      float4 v = *(const float4*)&Br[(size_t)(kk0 + row) * Nc + n0 + nn];
      *(float4*)&Bs[row][nn] = v;
    }
    __syncthreads();
#pragma unroll
    for (int k = 0; k < 32; ++k) {
      float a[4], b[4];
#pragma unroll
      for (int i = 0; i < 4; ++i) a[i] = As[k][ty * 4 + i];
#pragma unroll
      for (int j = 0; j < 4; ++j) b[j] = Bs[k][tx * 4 + j];
#pragma unroll
      for (int i = 0; i < 4; ++i)
#pragma unroll
        for (int j = 0; j < 4; ++j) acc[i][j] += a[i] * b[j];
    }
    __syncthreads();
  }
#pragma unroll
  for (int i = 0; i < 4; ++i) {
    int gm = m0 + ty * 4 + i;
    if (gm < M) {
      float4 v = make_float4(acc[i][0], acc[i][1], acc[i][2], acc[i][3]);
      *(float4*)&Cr[(size_t)gm * Nc + n0 + tx * 4] = v;
    }
  }
}

// ---------------- attention logits: a_i = xw.q, a_j = xw.k ----------------
// xw:[R*N, C]; q,k:[C,H]; ai,aj:[R*N, H]. One wave per (r,node).
template <int C, int H>
__global__ __launch_bounds__(256) void k_attn_logits(const float* __restrict__ xw,
                                                     const float* __restrict__ q,
                                                     const float* __restrict__ k,
                                                     float* __restrict__ ai,
                                                     float* __restrict__ aj,
                                                     int totalRows) {
  constexpr int VEC = C / WAVE;
  int wid  = (blockIdx.x * blockDim.x + threadIdx.x) >> 6;
  int lane = threadIdx.x & 63;
  if (wid >= totalRows) return;
  const float* row = xw + (size_t)wid * C;
  float xv[VEC];
#pragma unroll
  for (int v = 0; v < VEC; ++v) xv[v] = row[lane * VEC + v];
#pragma unroll
  for (int h = 0; h < H; ++h) {
    float pq = 0.f, pk = 0.f;
#pragma unroll
    for (int v = 0; v < VEC; ++v) {
      int c = lane * VEC + v;
      pq += xv[v] * q[c * H + h];
      pk += xv[v] * k[c * H + h];
    }
#pragma unroll
    for (int o = 32; o; o >>= 1) {
      pq += __shfl_xor(pq, o);
      pk += __shfl_xor(pk, o);
    }
    if (lane == 0) {
      ai[(size_t)wid * H + h] = pq;
      aj[(size_t)wid * H + h] = pk;
    }
  }
}

// ---------------- per-dst aggregation with online segment softmax ----------
// wave per node. 3 passes over its CSR edge list:
//   1: per-head max of leaky(a_i[et,dst]+a_j[et,src], 0.2)
//   2: per-head sum of exp(alpha - max)
//   3: out[c] += exp(alpha-max)/(sum+1e-16) * xw[et,src,c]
// epilogue: leaky(out + bias, 0.01)
template <int C, int H>
__global__ __launch_bounds__(256) void k_agg(const int* __restrict__ rowptr,
                                             const int* __restrict__ csr,
                                             const int* __restrict__ srcIdx,
                                             const int* __restrict__ etype,
                                             const float* __restrict__ ai,
                                             const float* __restrict__ aj,
                                             const float* __restrict__ xw,
                                             const float* __restrict__ bias,
                                             float* __restrict__ out, int nNodes) {
  constexpr int VEC = C / WAVE;
  constexpr int OC  = C / H;  // out channels per head
  int wid  = (blockIdx.x * blockDim.x + threadIdx.x) >> 6;
  int lane = threadIdx.x & 63;
  if (wid >= nNodes) return;
  const int node  = wid;
  const int start = rowptr[node];
  const int end   = rowptr[node + 1];

  float aiv[2][H];
#pragma unroll
  for (int rr = 0; rr < 2; ++rr)
#pragma unroll
    for (int h = 0; h < H; ++h)
      aiv[rr][h] = ai[((size_t)rr * nNodes + node) * H + h];

  // pass 1: segment max
  float m[H];
#pragma unroll
  for (int h = 0; h < H; ++h) m[h] = -1e30f;
  for (int i = start + lane; i < end; i += WAVE) {
    int e = csr[i];
    int s = srcIdx[e];
    int t = etype[e];
#pragma unroll
    for (int h = 0; h < H; ++h) {
      float a = aiv[t][h] + aj[((size_t)t * nNodes + s) * H + h];
      a = a > 0.f ? a : 0.2f * a;
      m[h] = fmaxf(m[h], a);
    }
  }
#pragma unroll
  for (int h = 0; h < H; ++h)
#pragma unroll
    for (int o = 32; o; o >>= 1) m[h] = fmaxf(m[h], __shfl_xor(m[h], o));

  // pass 2: sum of exp
  float ssum[H];
#pragma unroll
  for (int h = 0; h < H; ++h) ssum[h] = 0.f;
  for (int i = start + lane; i < end; i += WAVE) {
    int e = csr[i];
    int s = srcIdx[e];
    int t = etype[e];
#pragma unroll
    for (int h = 0; h < H; ++h) {
      float a = aiv[t][h] + aj[((size_t)t * nNodes + s) * H + h];
      a = a > 0.f ? a : 0.2f * a;
      ssum[h] += expf(a - m[h]);
    }
  }
  float inv[H];
#pragma unroll
  for (int h = 0; h < H; ++h) {
#pragma unroll
    for (int o = 32; o; o >>= 1) ssum[h] += __shfl_xor(ssum[h], o);
    inv[h] = 1.f / (ssum[h] + 1e-16f);
  }

  // pass 3: weighted accumulate (whole wave per edge, vector row load)
  const int myhead = (lane * VEC) / OC;
  float acc[VEC] = {};
  for (int i = start; i < end; ++i) {
    int e = csr[i];
    int s = srcIdx[e];
    int t = etype[e];
    float a = aiv[t][myhead] + aj[((size_t)t * nNodes + s) * H + myhead];
    a = a > 0.f ? a : 0.2f * a;
    float coef = expf(a - m[myhead]) * inv[myhead];
    const float* row = xw + ((size_t)t * nNodes + s) * C + lane * VEC;
    if constexpr (VEC == 4) {
      float4 rv = *(const float4*)row;
      acc[0] += coef * rv.x; acc[1] += coef * rv.y;
      acc[2] += coef * rv.z; acc[3] += coef * rv.w;
    } else {
      float2 rv = *(const float2*)row;
      acc[0] += coef * rv.x; acc[1] += coef * rv.y;
    }
  }
#pragma unroll
  for (int v = 0; v < VEC; ++v) {
    int c = lane * VEC + v;
    float xo = acc[v] + bias[c];
    out[(size_t)node * C + c] = xo > 0.f ? xo : 0.01f * xo;
  }
}

// ---------------- BatchNorm ----------------
__global__ void k_bn_stats(const float* __restrict__ h, double* __restrict__ sum,
                           double* __restrict__ sumsq, int nNodes, int C) {
  int col = threadIdx.x;           // blockDim.x == C
  int r0 = blockIdx.x * 256;
  int r1 = r0 + 256; if (r1 > nNodes) r1 = nNodes;
  double s = 0.0, s2 = 0.0;
  for (int r = r0; r < r1; ++r) {
    float v = h[(size_t)r * C + col];
    s += v;
    s2 += (double)v * (double)v;
  }
  atomicAdd(&sum[col], s);
  atomicAdd(&sumsq[col], s2);
}

__global__ void k_bn_finalize(const double* __restrict__ sum,
                              const double* __restrict__ sumsq,
                              const float* __restrict__ g,
                              const float* __restrict__ be,
                              float* __restrict__ scale,
                              float* __restrict__ shift, int nNodes, int C) {
  int c = blockIdx.x * blockDim.x + threadIdx.x;
  if (c >= C) return;
  double mu  = sum[c] / nNodes;
  double var = sumsq[c] / nNodes - mu * mu;
  float rs = (float)(1.0 / sqrt(var + 1e-5));
  float sc = g[c] * rs;
  scale[c] = sc;
  shift[c] = be[c] - (float)mu * sc;
}

__global__ __launch_bounds__(256) void k_bn_apply(float* __restrict__ h,
                                                  const float* __restrict__ scale,
                                                  const float* __restrict__ shift,
                                                  int n4, int Cmask) {
  int i = blockIdx.x * blockDim.x + threadIdx.x;
  if (i >= n4) return;
  float4 v = ((float4*)h)[i];
  int c = (i * 4) & Cmask;
  v.x = v.x * scale[c + 0] + shift[c + 0];
  v.y = v.y * scale[c + 1] + shift[c + 1];
  v.z = v.z * scale[c + 2] + shift[c + 2];
  v.w = v.w * scale[c + 3] + shift[c + 3];
  ((float4*)h)[i] = v;
}

// ---------------- head: gather idx rows, sigmoid(h @ wm + bm) -------------
__global__ __launch_bounds__(256) void k_head(const float* __restrict__ h,
                                              const int* __restrict__ idx,
                                              const float* __restrict__ wm,
                                              const float* __restrict__ bm,
                                              float* __restrict__ outH,
                                              float* __restrict__ outP, int kSel) {
  int wid  = (blockIdx.x * blockDim.x + threadIdx.x) >> 6;
  int lane = threadIdx.x & 63;
  if (wid >= kSel) return;
  int node = idx[wid];
  const float* row = h + (size_t)node * 128;
  float2 v = *(const float2*)&row[lane * 2];
  *(float2*)&outH[(size_t)wid * 128 + lane * 2] = v;
  float p0 = v.x * wm[(lane * 2) * 5 + 0] + v.y * wm[(lane * 2 + 1) * 5 + 0];
  float p1 = v.x * wm[(lane * 2) * 5 + 1] + v.y * wm[(lane * 2 + 1) * 5 + 1];
  float p2 = v.x * wm[(lane * 2) * 5 + 2] + v.y * wm[(lane * 2 + 1) * 5 + 2];
  float p3 = v.x * wm[(lane * 2) * 5 + 3] + v.y * wm[(lane * 2 + 1) * 5 + 3];
  float p4 = v.x * wm[(lane * 2) * 5 + 4] + v.y * wm[(lane * 2 + 1) * 5 + 4];
#pragma unroll
  for (int o = 32; o; o >>= 1) {
    p0 += __shfl_xor(p0, o); p1 += __shfl_xor(p1, o); p2 += __shfl_xor(p2, o);
    p3 += __shfl_xor(p3, o); p4 += __shfl_xor(p4, o);
  }
  if (lane == 0) {
    float lg[5] = {p0 + bm[0], p1 + bm[1], p2 + bm[2], p3 + bm[3], p4 + bm[4]};
    float* o = &outP[(size_t)wid * 5];
    o[0] = 1.f / (1.f + expf(-lg[0]));
    o[1] = 1.f / (1.f + expf(-lg[1]));
    o[2] = 1.f / (1.f + expf(-lg[2]));
    o[3] = 1.f / (1.f + expf(-lg[3]));
    o[4] = 1.f / (1.f + expf(-lg[4]));
  }
}

// ---------------------------------------------------------------------------
extern "C" void kernel_launch(void* const* d_in, const int* in_sizes, int n_in,
                              void* d_out, int out_size, void* d_ws, size_t ws_size,
                              hipStream_t stream) {
  const float* x    = (const float*)d_in[0];
  const int*   ei   = (const int*)d_in[1];
  const int*   etyp = (const int*)d_in[2];
  const int*   idx  = (const int*)d_in[3];
  const float* w0   = (const float*)d_in[4];
  const float* q0   = (const float*)d_in[5];
  const float* k0   = (const float*)d_in[6];
  const float* b0   = (const float*)d_in[7];
  const float* g0   = (const float*)d_in[8];
  const float* be0  = (const float*)d_in[9];
  const float* w1   = (const float*)d_in[10];
  const float* q1   = (const float*)d_in[11];
  const float* k1   = (const float*)d_in[12];
  const float* b1   = (const float*)d_in[13];
  const float* g1   = (const float*)d_in[14];
  const float* be1  = (const float*)d_in[15];
  const float* wm   = (const float*)d_in[16];
  const float* bm   = (const float*)d_in[17];

  const int N    = in_sizes[0] / 128;   // 50000
  const int E    = in_sizes[1] / 2;     // 800000
  const int kSel = in_sizes[3];         // 4096
  const int* srcIdx = ei;
  const int* dstIdx = ei + E;

  // ---- workspace carve (256B aligned) ----
  size_t off = 0;
  auto carve = [&](size_t bytes) -> void* {
    off = (off + 255) & ~(size_t)255;
    void* p = (char*)d_ws + off;
    off += bytes;
    return p;
  };
  int*    deg     = (int*)carve((size_t)N * 4);
  int*    rowptr  = (int*)carve((size_t)(N + 1) * 4);
  int*    cursor  = (int*)carve((size_t)N * 4);
  int*    csr     = (int*)carve((size_t)E * 4);
  float*  xw      = (float*)carve((size_t)2 * N * 256 * 4);  // reused layer1 (half)
  float*  ai      = (float*)carve((size_t)2 * N * 2 * 4);
  float*  aj      = (float*)carve((size_t)2 * N * 2 * 4);
  float*  h0      = (float*)carve((size_t)N * 256 * 4);
  float*  h1      = (float*)carve((size_t)N * 128 * 4);
  double* dsum    = (double*)carve(256 * 8);
  double* dsumsq  = (double*)carve(256 * 8);
  float*  scl     = (float*)carve(256 * 4);
  float*  shf     = (float*)carve(256 * 4);

  float* outH = (float*)d_out;
  float* outP = outH + (size_t)kSel * 128;

  const int eb = (E + 255) / 256;
  const int nb = (N + 255) / 256;

  // ---- CSR build ----
  hipMemsetAsync(deg, 0, (size_t)N * 4, stream);
  k_hist<<<eb, 256, 0, stream>>>(dstIdx, deg, E);
  k_scan<<<1, 256, 0, stream>>>(deg, rowptr, N);
  k_copy_int<<<nb, 256, 0, stream>>>(rowptr, cursor, N);
  k_scatter<<<eb, 256, 0, stream>>>(dstIdx, cursor, csr, E);

  // ---- layer 0 ----
  {
    dim3 grid(256 / 64, (N + 63) / 64, 2);
    k_gemm<<<grid, 256, 0, stream>>>(x, w0, xw, N, 128, 256);
  }
  k_attn_logits<256, 2><<<(2 * N * WAVE + 255) / 256, 256, 0, stream>>>(
      xw, q0, k0, ai, aj, 2 * N);
  k_agg<256, 2><<<(N * WAVE + 255) / 256, 256, 0, stream>>>(
      rowptr, csr, srcIdx, etyp, ai, aj, xw, b0, h0, N);
  hipMemsetAsync(dsum, 0, 256 * 8, stream);
  hipMemsetAsync(dsumsq, 0, 256 * 8, stream);
  k_bn_stats<<<(N + 255) / 256, 256, 0, stream>>>(h0, dsum, dsumsq, N, 256);
  k_bn_finalize<<<1, 256, 0, stream>>>(dsum, dsumsq, g0, be0, scl, shf, N, 256);
  k_bn_apply<<<((N * 256 / 4) + 255) / 256, 256, 0, stream>>>(
      h0, scl, shf, N * 256 / 4, 255);

  // ---- layer 1 ----
  {
    dim3 grid(128 / 64, (N + 63) / 64, 2);
    k_gemm<<<grid, 256, 0, stream>>>(h0, w1, xw, N, 256, 128);
  }
  k_attn_logits<128, 1><<<(2 * N * WAVE + 255) / 256, 256, 0, stream>>>(
      xw, q1, k1, ai, aj, 2 * N);
  k_agg<128, 1><<<(N * WAVE + 255) / 256, 256, 0, stream>>>(
      rowptr, csr, srcIdx, etyp, ai, aj, xw, b1, h1, N);
  hipMemsetAsync(dsum, 0, 128 * 8, stream);
  hipMemsetAsync(dsumsq, 0, 128 * 8, stream);
  k_bn_stats<<<(N + 255) / 256, 128, 0, stream>>>(h1, dsum, dsumsq, N, 128);
  k_bn_finalize<<<1, 128, 0, stream>>>(dsum, dsumsq, g1, be1, scl, shf, N, 128);
  k_bn_apply<<<((N * 128 / 4) + 255) / 256, 256, 0, stream>>>(
      h1, scl, shf, N * 128 / 4, 127);

  // ---- head ----
  k_head<<<(kSel * WAVE + 255) / 256, 256, 0, stream>>>(
      h1, idx, wm, bm, outH, outP, kSel);
}

// Round 2
// 1047.843 us; speedup vs baseline: 1.1441x; 1.1441x over previous
//
#include <hip/hip_runtime.h>
#include <hip/hip_bf16.h>
#include <math.h>

// ---------------------------------------------------------------------------
// RGAT (2 relations) x2 + BatchNorm + head, fp32.
//   1. CSR-by-dst (hist -> scan -> scatter)
//   2. xw[r] = x @ W[r]  (tiled fp32 GEMM; optional fused per-K scale/shift on A)
//   3. a_i = xw . q, a_j = xw . k
//   4. per-dst aggregation: register-resident softmax coefs, shfl-broadcast
//      gather loop (MLP-friendly), normalize at end
//   5. BN stats -> finalize; apply fused into consumer (gemm1 / head)
// ---------------------------------------------------------------------------

#define WAVE 64

// ---------------- CSR build ----------------
__global__ __launch_bounds__(256) void k_hist(const int* __restrict__ dst,
                                              int* __restrict__ deg, int E) {
  int e = blockIdx.x * blockDim.x + threadIdx.x;
  if (e < E) atomicAdd(&deg[dst[e]], 1);
}

__global__ __launch_bounds__(256) void k_scan(const int* __restrict__ deg,
                                              int* __restrict__ rowptr, int n) {
  __shared__ int lsum[256];
  int t = threadIdx.x;
  int chunk = (n + 255) >> 8;
  int s0 = t * chunk;
  int s1 = s0 + chunk; if (s1 > n) s1 = n; if (s0 > n) s0 = n;
  int acc = 0;
  for (int i = s0; i < s1; ++i) acc += deg[i];
  lsum[t] = acc;
  __syncthreads();
  for (int o = 1; o < 256; o <<= 1) {
    int v = 0;
    if (t >= o) v = lsum[t - o];
    __syncthreads();
    if (t >= o) lsum[t] += v;
    __syncthreads();
  }
  int run = (t > 0) ? lsum[t - 1] : 0;
  for (int i = s0; i < s1; ++i) { rowptr[i] = run; run += deg[i]; }
  if (t == 255) rowptr[n] = lsum[255];
}

__global__ __launch_bounds__(256) void k_copy_int(const int* __restrict__ a,
                                                  int* __restrict__ b, int n) {
  int i = blockIdx.x * blockDim.x + threadIdx.x;
  if (i < n) b[i] = a[i];
}

__global__ __launch_bounds__(256) void k_scatter(const int* __restrict__ dst,
                                                 int* __restrict__ cursor,
                                                 int* __restrict__ csr, int E) {
  int e = blockIdx.x * blockDim.x + threadIdx.x;
  if (e < E) {
    int p = atomicAdd(&cursor[dst[e]], 1);
    csr[p] = e;
  }
}

// ---------------- fp32 GEMM: C[r] = f(A) @ B[r] ----------------
// A:[M,K] rowmajor, B:[R,K,Nc], C:[R,M,Nc]. Nc%64==0, K%32==0.
// If ascale != nullptr, A is transformed elementwise: a*ascale[k]+ashift[k].
__global__ __launch_bounds__(256) void k_gemm(const float* __restrict__ A,
                                              const float* __restrict__ B,
                                              float* __restrict__ C,
                                              const float* __restrict__ ascale,
                                              const float* __restrict__ ashift,
                                              int M, int K, int Nc) {
  const int r  = blockIdx.z;
  const int m0 = blockIdx.y * 64;
  const int n0 = blockIdx.x * 64;
  const float* Br = B + (size_t)r * K * Nc;
  float* Cr = C + (size_t)r * M * Nc;
  __shared__ float As[32][65];
  __shared__ float Bs[32][64];
  const int tid = threadIdx.x;
  const int tx = tid & 15, ty = tid >> 4;
  float acc[4][4] = {};
  for (int kk0 = 0; kk0 < K; kk0 += 32) {
    // stage A tile (64 rows x 32 k), transposed into As[k][m]
#pragma unroll
    for (int it = 0; it < 2; ++it) {
      int row = (tid >> 3) + it * 32;
      int kk  = (tid & 7) * 4;
      int gm  = m0 + row;
      float4 v = make_float4(0.f, 0.f, 0.f, 0.f);
      if (gm < M) v = *(const float4*)&A[(size_t)gm * K + kk0 + kk];
      if (ascale) {
        v.x = v.x * ascale[kk0 + kk + 0] + ashift[kk0 + kk + 0];
        v.y = v.y * ascale[kk0 + kk + 1] + ashift[kk0 + kk + 1];
        v.z = v.z * ascale[kk0 + kk + 2] + ashift[kk0 + kk + 2];
        v.w = v.w * ascale[kk0 + kk + 3] + ashift[kk0 + kk + 3];
      }
      As[kk + 0][row] = v.x; As[kk + 1][row] = v.y;
      As[kk + 2][row] = v.z; As[kk + 3][row] = v.w;
    }
    // stage B tile (32 k x 64 n)
#pragma unroll
    for (int it = 0; it < 2; ++it) {
      int row = (tid >> 4) + it * 16;
      int nn  = (tid & 15) * 4;
      float4 v = *(const float4*)&Br[(size_t)(kk0 + row) * Nc + n0 + nn];
      *(float4*)&Bs[row][nn] = v;
    }
    __syncthreads();
#pragma unroll
    for (int k = 0; k < 32; ++k) {
      float a[4], b[4];
#pragma unroll
      for (int i = 0; i < 4; ++i) a[i] = As[k][ty * 4 + i];
#pragma unroll
      for (int j = 0; j < 4; ++j) b[j] = Bs[k][tx * 4 + j];
#pragma unroll
      for (int i = 0; i < 4; ++i)
#pragma unroll
        for (int j = 0; j < 4; ++j) acc[i][j] += a[i] * b[j];
    }
    __syncthreads();
  }
#pragma unroll
  for (int i = 0; i < 4; ++i) {
    int gm = m0 + ty * 4 + i;
    if (gm < M) {
      float4 v = make_float4(acc[i][0], acc[i][1], acc[i][2], acc[i][3]);
      *(float4*)&Cr[(size_t)gm * Nc + n0 + tx * 4] = v;
    }
  }
}

// ---------------- attention logits: a_i = xw.q, a_j = xw.k ----------------
template <int C, int H>
__global__ __launch_bounds__(256) void k_attn_logits(const float* __restrict__ xw,
                                                     const float* __restrict__ q,
                                                     const float* __restrict__ k,
                                                     float* __restrict__ ai,
                                                     float* __restrict__ aj,
                                                     int totalRows) {
  constexpr int VEC = C / WAVE;
  int wid  = (blockIdx.x * blockDim.x + threadIdx.x) >> 6;
  int lane = threadIdx.x & 63;
  if (wid >= totalRows) return;
  const float* row = xw + (size_t)wid * C;
  float xv[VEC];
#pragma unroll
  for (int v = 0; v < VEC; ++v) xv[v] = row[lane * VEC + v];
#pragma unroll
  for (int h = 0; h < H; ++h) {
    float pq = 0.f, pk = 0.f;
#pragma unroll
    for (int v = 0; v < VEC; ++v) {
      int c = lane * VEC + v;
      pq += xv[v] * q[c * H + h];
      pk += xv[v] * k[c * H + h];
    }
#pragma unroll
    for (int o = 32; o; o >>= 1) {
      pq += __shfl_xor(pq, o);
      pk += __shfl_xor(pk, o);
    }
    if (lane == 0) {
      ai[(size_t)wid * H + h] = pq;
      aj[(size_t)wid * H + h] = pk;
    }
  }
}

// ---------------- per-dst aggregation, MLP-friendly ----------
// wave per node. Chunk of <=64 edges: lane-parallel meta load + coef compute,
// then shfl-broadcast gather loop (loads independent -> deep pipelining).
// Normalization applied once at the end: out = (sum e_i * row_i) * inv.
template <int C, int H>
__global__ __launch_bounds__(256) void k_agg(const int* __restrict__ rowptr,
                                             const int* __restrict__ csr,
                                             const int* __restrict__ srcIdx,
                                             const int* __restrict__ etype,
                                             const float* __restrict__ ai,
                                             const float* __restrict__ aj,
                                             const float* __restrict__ xw,
                                             const float* __restrict__ bias,
                                             float* __restrict__ out, int nNodes) {
  constexpr int VEC = C / WAVE;   // 4 (L0) or 2 (L1)
  constexpr int OC  = C / H;      // channels per head
  int wid  = (blockIdx.x * blockDim.x + threadIdx.x) >> 6;
  int lane = threadIdx.x & 63;
  if (wid >= nNodes) return;
  const int node  = wid;
  const int start = rowptr[node];
  const int end   = rowptr[node + 1];
  const int deg   = end - start;
  const int myhead = (lane * VEC) / OC;   // 0..H-1

  float aiv[2][H];
#pragma unroll
  for (int rr = 0; rr < 2; ++rr)
#pragma unroll
    for (int h = 0; h < H; ++h)
      aiv[rr][h] = ai[((size_t)rr * nNodes + node) * H + h];

  float acc[VEC] = {};
  float ssum[H] = {};
  float m[H];

  if (deg <= WAVE) {
    // ---- fast path: whole segment in one register chunk ----
    int i = start + lane;
    bool valid = i < end;
    int e = valid ? csr[i] : 0;
    int s = valid ? srcIdx[e] : 0;
    int t = valid ? etype[e] : 0;
    float a[H], eh[H];
#pragma unroll
    for (int h = 0; h < H; ++h) {
      float v = aiv[t][h] + aj[((size_t)t * nNodes + s) * H + h];
      v = v > 0.f ? v : 0.2f * v;
      a[h] = valid ? v : -1e30f;
      m[h] = a[h];
    }
#pragma unroll
    for (int h = 0; h < H; ++h)
#pragma unroll
      for (int o = 32; o; o >>= 1) m[h] = fmaxf(m[h], __shfl_xor(m[h], o));
#pragma unroll
    for (int h = 0; h < H; ++h) {
      eh[h] = valid ? expf(a[h] - m[h]) : 0.f;
      ssum[h] = eh[h];
    }
#pragma unroll 4
    for (int j = 0; j < deg; ++j) {
      int   sj = __shfl(s, j);
      int   tj = __shfl(t, j);
      float c0 = __shfl(eh[0], j);
      float coef;
      if (H == 1) coef = c0;
      else { float c1 = __shfl(eh[H - 1], j); coef = myhead ? c1 : c0; }
      const float* row = xw + ((size_t)tj * nNodes + sj) * C + lane * VEC;
      if constexpr (VEC == 4) {
        float4 rv = *(const float4*)row;
        acc[0] += coef * rv.x; acc[1] += coef * rv.y;
        acc[2] += coef * rv.z; acc[3] += coef * rv.w;
      } else {
        float2 rv = *(const float2*)row;
        acc[0] += coef * rv.x; acc[1] += coef * rv.y;
      }
    }
  } else {
    // ---- generic path ----
#pragma unroll
    for (int h = 0; h < H; ++h) m[h] = -1e30f;
    for (int i = start + lane; i < end; i += WAVE) {
      int e = csr[i];
      int s = srcIdx[e];
      int t = etype[e];
#pragma unroll
      for (int h = 0; h < H; ++h) {
        float v = aiv[t][h] + aj[((size_t)t * nNodes + s) * H + h];
        v = v > 0.f ? v : 0.2f * v;
        m[h] = fmaxf(m[h], v);
      }
    }
#pragma unroll
    for (int h = 0; h < H; ++h)
#pragma unroll
      for (int o = 32; o; o >>= 1) m[h] = fmaxf(m[h], __shfl_xor(m[h], o));

    for (int base = start; base < end; base += WAVE) {
      int i = base + lane;
      bool valid = i < end;
      int e = valid ? csr[i] : 0;
      int s = valid ? srcIdx[e] : 0;
      int t = valid ? etype[e] : 0;
      float eh[H];
#pragma unroll
      for (int h = 0; h < H; ++h) {
        float v = aiv[t][h] + aj[((size_t)t * nNodes + s) * H + h];
        v = v > 0.f ? v : 0.2f * v;
        eh[h] = valid ? expf(v - m[h]) : 0.f;
        ssum[h] += eh[h];
      }
      int cnt = end - base; if (cnt > WAVE) cnt = WAVE;
#pragma unroll 4
      for (int j = 0; j < cnt; ++j) {
        int   sj = __shfl(s, j);
        int   tj = __shfl(t, j);
        float c0 = __shfl(eh[0], j);
        float coef;
        if (H == 1) coef = c0;
        else { float c1 = __shfl(eh[H - 1], j); coef = myhead ? c1 : c0; }
        const float* row = xw + ((size_t)tj * nNodes + sj) * C + lane * VEC;
        if constexpr (VEC == 4) {
          float4 rv = *(const float4*)row;
          acc[0] += coef * rv.x; acc[1] += coef * rv.y;
          acc[2] += coef * rv.z; acc[3] += coef * rv.w;
        } else {
          float2 rv = *(const float2*)row;
          acc[0] += coef * rv.x; acc[1] += coef * rv.y;
        }
      }
    }
  }

#pragma unroll
  for (int h = 0; h < H; ++h)
#pragma unroll
    for (int o = 32; o; o >>= 1) ssum[h] += __shfl_xor(ssum[h], o);
  float inv = 1.f / (ssum[myhead] + 1e-16f);

#pragma unroll
  for (int v = 0; v < VEC; ++v) {
    int c = lane * VEC + v;
    float xo = acc[v] * inv + bias[c];
    out[(size_t)node * C + c] = xo > 0.f ? xo : 0.01f * xo;
  }
}

// ---------------- BatchNorm stats ----------------
__global__ void k_bn_stats(const float* __restrict__ h, double* __restrict__ sum,
                           double* __restrict__ sumsq, int nNodes, int C) {
  int col = threadIdx.x;           // blockDim.x == C
  int r0 = blockIdx.x * 256;
  int r1 = r0 + 256; if (r1 > nNodes) r1 = nNodes;
  double s = 0.0, s2 = 0.0;
  for (int r = r0; r < r1; ++r) {
    float v = h[(size_t)r * C + col];
    s += v;
    s2 += (double)v * (double)v;
  }
  atomicAdd(&sum[col], s);
  atomicAdd(&sumsq[col], s2);
}

__global__ void k_bn_finalize(const double* __restrict__ sum,
                              const double* __restrict__ sumsq,
                              const float* __restrict__ g,
                              const float* __restrict__ be,
                              float* __restrict__ scale,
                              float* __restrict__ shift, int nNodes, int C) {
  int c = blockIdx.x * blockDim.x + threadIdx.x;
  if (c >= C) return;
  double mu  = sum[c] / nNodes;
  double var = sumsq[c] / nNodes - mu * mu;
  float rs = (float)(1.0 / sqrt(var + 1e-5));
  float sc = g[c] * rs;
  scale[c] = sc;
  shift[c] = be[c] - (float)mu * sc;
}

// ---------------- head: gather idx rows, fused BN1 apply, sigmoid ---------
__global__ __launch_bounds__(256) void k_head(const float* __restrict__ h,
                                              const int* __restrict__ idx,
                                              const float* __restrict__ scl,
                                              const float* __restrict__ shf,
                                              const float* __restrict__ wm,
                                              const float* __restrict__ bm,
                                              float* __restrict__ outH,
                                              float* __restrict__ outP, int kSel) {
  int wid  = (blockIdx.x * blockDim.x + threadIdx.x) >> 6;
  int lane = threadIdx.x & 63;
  if (wid >= kSel) return;
  int node = idx[wid];
  const float* row = h + (size_t)node * 128;
  int c = lane * 2;
  float2 v = *(const float2*)&row[c];
  v.x = v.x * scl[c + 0] + shf[c + 0];
  v.y = v.y * scl[c + 1] + shf[c + 1];
  *(float2*)&outH[(size_t)wid * 128 + c] = v;
  float p0 = v.x * wm[c * 5 + 0] + v.y * wm[(c + 1) * 5 + 0];
  float p1 = v.x * wm[c * 5 + 1] + v.y * wm[(c + 1) * 5 + 1];
  float p2 = v.x * wm[c * 5 + 2] + v.y * wm[(c + 1) * 5 + 2];
  float p3 = v.x * wm[c * 5 + 3] + v.y * wm[(c + 1) * 5 + 3];
  float p4 = v.x * wm[c * 5 + 4] + v.y * wm[(c + 1) * 5 + 4];
#pragma unroll
  for (int o = 32; o; o >>= 1) {
    p0 += __shfl_xor(p0, o); p1 += __shfl_xor(p1, o); p2 += __shfl_xor(p2, o);
    p3 += __shfl_xor(p3, o); p4 += __shfl_xor(p4, o);
  }
  if (lane == 0) {
    float lg[5] = {p0 + bm[0], p1 + bm[1], p2 + bm[2], p3 + bm[3], p4 + bm[4]};
    float* o = &outP[(size_t)wid * 5];
    o[0] = 1.f / (1.f + expf(-lg[0]));
    o[1] = 1.f / (1.f + expf(-lg[1]));
    o[2] = 1.f / (1.f + expf(-lg[2]));
    o[3] = 1.f / (1.f + expf(-lg[3]));
    o[4] = 1.f / (1.f + expf(-lg[4]));
  }
}

// ---------------------------------------------------------------------------
extern "C" void kernel_launch(void* const* d_in, const int* in_sizes, int n_in,
                              void* d_out, int out_size, void* d_ws, size_t ws_size,
                              hipStream_t stream) {
  const float* x    = (const float*)d_in[0];
  const int*   ei   = (const int*)d_in[1];
  const int*   etyp = (const int*)d_in[2];
  const int*   idx  = (const int*)d_in[3];
  const float* w0   = (const float*)d_in[4];
  const float* q0   = (const float*)d_in[5];
  const float* k0   = (const float*)d_in[6];
  const float* b0   = (const float*)d_in[7];
  const float* g0   = (const float*)d_in[8];
  const float* be0  = (const float*)d_in[9];
  const float* w1   = (const float*)d_in[10];
  const float* q1   = (const float*)d_in[11];
  const float* k1   = (const float*)d_in[12];
  const float* b1   = (const float*)d_in[13];
  const float* g1   = (const float*)d_in[14];
  const float* be1  = (const float*)d_in[15];
  const float* wm   = (const float*)d_in[16];
  const float* bm   = (const float*)d_in[17];

  const int N    = in_sizes[0] / 128;   // 50000
  const int E    = in_sizes[1] / 2;     // 800000
  const int kSel = in_sizes[3];         // 4096
  const int* srcIdx = ei;
  const int* dstIdx = ei + E;

  // ---- workspace carve (256B aligned) ----
  size_t off = 0;
  auto carve = [&](size_t bytes) -> void* {
    off = (off + 255) & ~(size_t)255;
    void* p = (char*)d_ws + off;
    off += bytes;
    return p;
  };
  int*    deg     = (int*)carve((size_t)N * 4);
  int*    rowptr  = (int*)carve((size_t)(N + 1) * 4);
  int*    cursor  = (int*)carve((size_t)N * 4);
  int*    csr     = (int*)carve((size_t)E * 4);
  float*  xw      = (float*)carve((size_t)2 * N * 256 * 4);  // reused layer1 (half)
  float*  ai      = (float*)carve((size_t)2 * N * 2 * 4);
  float*  aj      = (float*)carve((size_t)2 * N * 2 * 4);
  float*  h0      = (float*)carve((size_t)N * 256 * 4);
  float*  h1      = (float*)carve((size_t)N * 128 * 4);
  double* dsum    = (double*)carve(256 * 8);
  double* dsumsq  = (double*)carve(256 * 8);
  float*  scl     = (float*)carve(256 * 4);
  float*  shf     = (float*)carve(256 * 4);

  float* outH = (float*)d_out;
  float* outP = outH + (size_t)kSel * 128;

  const int eb = (E + 255) / 256;
  const int nb = (N + 255) / 256;

  // ---- CSR build ----
  hipMemsetAsync(deg, 0, (size_t)N * 4, stream);
  k_hist<<<eb, 256, 0, stream>>>(dstIdx, deg, E);
  k_scan<<<1, 256, 0, stream>>>(deg, rowptr, N);
  k_copy_int<<<nb, 256, 0, stream>>>(rowptr, cursor, N);
  k_scatter<<<eb, 256, 0, stream>>>(dstIdx, cursor, csr, E);

  // ---- layer 0 ----
  {
    dim3 grid(256 / 64, (N + 63) / 64, 2);
    k_gemm<<<grid, 256, 0, stream>>>(x, w0, xw, nullptr, nullptr, N, 128, 256);
  }
  k_attn_logits<256, 2><<<(2 * N * WAVE + 255) / 256, 256, 0, stream>>>(
      xw, q0, k0, ai, aj, 2 * N);
  k_agg<256, 2><<<(N * WAVE + 255) / 256, 256, 0, stream>>>(
      rowptr, csr, srcIdx, etyp, ai, aj, xw, b0, h0, N);
  hipMemsetAsync(dsum, 0, 256 * 8, stream);
  hipMemsetAsync(dsumsq, 0, 256 * 8, stream);
  k_bn_stats<<<(N + 255) / 256, 256, 0, stream>>>(h0, dsum, dsumsq, N, 256);
  k_bn_finalize<<<1, 256, 0, stream>>>(dsum, dsumsq, g0, be0, scl, shf, N, 256);

  // ---- layer 1 (BN0 apply fused into GEMM A-read) ----
  {
    dim3 grid(128 / 64, (N + 63) / 64, 2);
    k_gemm<<<grid, 256, 0, stream>>>(h0, w1, xw, scl, shf, N, 256, 128);
  }
  k_attn_logits<128, 1><<<(2 * N * WAVE + 255) / 256, 256, 0, stream>>>(
      xw, q1, k1, ai, aj, 2 * N);
  k_agg<128, 1><<<(N * WAVE + 255) / 256, 256, 0, stream>>>(
      rowptr, csr, srcIdx, etyp, ai, aj, xw, b1, h1, N);
  hipMemsetAsync(dsum, 0, 128 * 8, stream);
  hipMemsetAsync(dsumsq, 0, 128 * 8, stream);
  k_bn_stats<<<(N + 255) / 256, 128, 0, stream>>>(h1, dsum, dsumsq, N, 128);
  k_bn_finalize<<<1, 128, 0, stream>>>(dsum, dsumsq, g1, be1, scl, shf, N, 128);

  // ---- head (BN1 apply fused) ----
  k_head<<<(kSel * WAVE + 255) / 256, 256, 0, stream>>>(
      h1, idx, scl, shf, wm, bm, outH, outP, kSel);
}

// Round 3
// 903.633 us; speedup vs baseline: 1.3267x; 1.1596x over previous
//
#include <hip/hip_runtime.h>
#include <hip/hip_bf16.h>
#include <math.h>

// ---------------------------------------------------------------------------
// RGAT (2 relations) x2 + BatchNorm + head, fp32.
//   1. CSR-by-dst (hist -> scan(+cursor) -> scatter)
//   2. xw[r] = f(A) @ W[r]  (tiled fp32 GEMM, fused BN-apply on A,
//      fused attention-logit partials: ai=xw.q, aj=xw.k via atomics)
//   3. per-dst aggregation: register softmax coefs, shfl-broadcast gather
//   4. BN stats -> finalize; apply fused into consumer (gemm1 / head)
// ---------------------------------------------------------------------------

#define WAVE 64

// ---------------- CSR build ----------------
__global__ __launch_bounds__(256) void k_hist(const int* __restrict__ dst,
                                              int* __restrict__ deg, int E) {
  int e = blockIdx.x * blockDim.x + threadIdx.x;
  if (e < E) atomicAdd(&deg[dst[e]], 1);
}

__global__ __launch_bounds__(256) void k_scan(const int* __restrict__ deg,
                                              int* __restrict__ rowptr,
                                              int* __restrict__ cursor, int n) {
  __shared__ int lsum[256];
  int t = threadIdx.x;
  int chunk = (n + 255) >> 8;
  int s0 = t * chunk;
  int s1 = s0 + chunk; if (s1 > n) s1 = n; if (s0 > n) s0 = n;
  int acc = 0;
  for (int i = s0; i < s1; ++i) acc += deg[i];
  lsum[t] = acc;
  __syncthreads();
  for (int o = 1; o < 256; o <<= 1) {
    int v = 0;
    if (t >= o) v = lsum[t - o];
    __syncthreads();
    if (t >= o) lsum[t] += v;
    __syncthreads();
  }
  int run = (t > 0) ? lsum[t - 1] : 0;
  for (int i = s0; i < s1; ++i) {
    rowptr[i] = run;
    cursor[i] = run;
    run += deg[i];
  }
  if (t == 255) rowptr[n] = lsum[255];
}

__global__ __launch_bounds__(256) void k_scatter(const int* __restrict__ dst,
                                                 int* __restrict__ cursor,
                                                 int* __restrict__ csr, int E) {
  int e = blockIdx.x * blockDim.x + threadIdx.x;
  if (e < E) {
    int p = atomicAdd(&cursor[dst[e]], 1);
    csr[p] = e;
  }
}

// ---------------- fp32 GEMM + fused attention logits ----------------
// A:[M,K] rowmajor, B:[R,K,Nc], C:[R,M,Nc]. Nc%64==0, K%32==0.
// If ascale != nullptr: A elementwise a*ascale[k]+ashift[k] (fused BN apply).
// Epilogue: ai[(r*M+m)*H+h] += sum_n C[r][m][n]*qm[n*H+h]  (atomic partials)
//           aj[...]         += sum_n C[r][m][n]*km[n*H+h]
template <int H>
__global__ __launch_bounds__(256) void k_gemm_attn(
    const float* __restrict__ A, const float* __restrict__ B,
    float* __restrict__ C, const float* __restrict__ ascale,
    const float* __restrict__ ashift, const float* __restrict__ qm,
    const float* __restrict__ km, float* __restrict__ ai,
    float* __restrict__ aj, int M, int K, int Nc) {
  const int r  = blockIdx.z;
  const int m0 = blockIdx.y * 64;
  const int n0 = blockIdx.x * 64;
  const float* Br = B + (size_t)r * K * Nc;
  float* Cr = C + (size_t)r * M * Nc;
  __shared__ float As[32][68];   // stride 272B -> 16B aligned b128 reads
  __shared__ float Bs[32][64];
  const int tid = threadIdx.x;
  const int tx = tid & 15, ty = tid >> 4;
  float acc[4][4] = {};
  for (int kk0 = 0; kk0 < K; kk0 += 32) {
    // stage A tile (64 rows x 32 k), transposed into As[k][m]
#pragma unroll
    for (int it = 0; it < 2; ++it) {
      int row = (tid >> 3) + it * 32;
      int kk  = (tid & 7) * 4;
      int gm  = m0 + row;
      float4 v = make_float4(0.f, 0.f, 0.f, 0.f);
      if (gm < M) v = *(const float4*)&A[(size_t)gm * K + kk0 + kk];
      if (ascale) {
        v.x = v.x * ascale[kk0 + kk + 0] + ashift[kk0 + kk + 0];
        v.y = v.y * ascale[kk0 + kk + 1] + ashift[kk0 + kk + 1];
        v.z = v.z * ascale[kk0 + kk + 2] + ashift[kk0 + kk + 2];
        v.w = v.w * ascale[kk0 + kk + 3] + ashift[kk0 + kk + 3];
      }
      As[kk + 0][row] = v.x; As[kk + 1][row] = v.y;
      As[kk + 2][row] = v.z; As[kk + 3][row] = v.w;
    }
    // stage B tile (32 k x 64 n)
#pragma unroll
    for (int it = 0; it < 2; ++it) {
      int row = (tid >> 4) + it * 16;
      int nn  = (tid & 15) * 4;
      float4 v = *(const float4*)&Br[(size_t)(kk0 + row) * Nc + n0 + nn];
      *(float4*)&Bs[row][nn] = v;
    }
    __syncthreads();
#pragma unroll
    for (int k = 0; k < 32; ++k) {
      float4 a4 = *(const float4*)&As[k][ty * 4];
      float4 b4 = *(const float4*)&Bs[k][tx * 4];
      float a[4] = {a4.x, a4.y, a4.z, a4.w};
      float b[4] = {b4.x, b4.y, b4.z, b4.w};
#pragma unroll
      for (int i = 0; i < 4; ++i)
#pragma unroll
        for (int j = 0; j < 4; ++j) acc[i][j] += a[i] * b[j];
    }
    __syncthreads();
  }
  // C store
#pragma unroll
  for (int i = 0; i < 4; ++i) {
    int gm = m0 + ty * 4 + i;
    if (gm < M) {
      float4 v = make_float4(acc[i][0], acc[i][1], acc[i][2], acc[i][3]);
      *(float4*)&Cr[(size_t)gm * Nc + n0 + tx * 4] = v;
    }
  }
  // fused attention-logit partials
  float qv[4][H], kv[4][H];
#pragma unroll
  for (int j = 0; j < 4; ++j) {
    int gn = n0 + tx * 4 + j;
#pragma unroll
    for (int h = 0; h < H; ++h) {
      qv[j][h] = qm[gn * H + h];
      kv[j][h] = km[gn * H + h];
    }
  }
#pragma unroll
  for (int i = 0; i < 4; ++i) {
    int gm = m0 + ty * 4 + i;
#pragma unroll
    for (int h = 0; h < H; ++h) {
      float pq = 0.f, pk = 0.f;
#pragma unroll
      for (int j = 0; j < 4; ++j) {
        pq += acc[i][j] * qv[j][h];
        pk += acc[i][j] * kv[j][h];
      }
#pragma unroll
      for (int o = 8; o; o >>= 1) {
        pq += __shfl_xor(pq, o);
        pk += __shfl_xor(pk, o);
      }
      if (tx == 0 && gm < M) {
        atomicAdd(&ai[((size_t)r * M + gm) * H + h], pq);
        atomicAdd(&aj[((size_t)r * M + gm) * H + h], pk);
      }
    }
  }
}

// ---------------- per-dst aggregation, MLP-friendly ----------
template <int C, int H>
__global__ __launch_bounds__(256) void k_agg(const int* __restrict__ rowptr,
                                             const int* __restrict__ csr,
                                             const int* __restrict__ srcIdx,
                                             const int* __restrict__ etype,
                                             const float* __restrict__ ai,
                                             const float* __restrict__ aj,
                                             const float* __restrict__ xw,
                                             const float* __restrict__ bias,
                                             float* __restrict__ out, int nNodes) {
  constexpr int VEC = C / WAVE;   // 4 (L0) or 2 (L1)
  constexpr int OC  = C / H;      // channels per head
  int wid  = (blockIdx.x * blockDim.x + threadIdx.x) >> 6;
  int lane = threadIdx.x & 63;
  if (wid >= nNodes) return;
  const int node  = wid;
  const int start = rowptr[node];
  const int end   = rowptr[node + 1];
  const int deg   = end - start;
  const int myhead = (lane * VEC) / OC;   // 0..H-1

  float aiv[2][H];
#pragma unroll
  for (int rr = 0; rr < 2; ++rr)
#pragma unroll
    for (int h = 0; h < H; ++h)
      aiv[rr][h] = ai[((size_t)rr * nNodes + node) * H + h];

  float acc[VEC] = {};
  float ssum[H] = {};
  float m[H];

  if (deg <= WAVE) {
    int i = start + lane;
    bool valid = i < end;
    int e = valid ? csr[i] : 0;
    int s = valid ? srcIdx[e] : 0;
    int t = valid ? etype[e] : 0;
    float a[H], eh[H];
#pragma unroll
    for (int h = 0; h < H; ++h) {
      float v = aiv[t][h] + aj[((size_t)t * nNodes + s) * H + h];
      v = v > 0.f ? v : 0.2f * v;
      a[h] = valid ? v : -1e30f;
      m[h] = a[h];
    }
#pragma unroll
    for (int h = 0; h < H; ++h)
#pragma unroll
      for (int o = 32; o; o >>= 1) m[h] = fmaxf(m[h], __shfl_xor(m[h], o));
#pragma unroll
    for (int h = 0; h < H; ++h) {
      eh[h] = valid ? expf(a[h] - m[h]) : 0.f;
      ssum[h] = eh[h];
    }
#pragma unroll 4
    for (int j = 0; j < deg; ++j) {
      int   sj = __shfl(s, j);
      int   tj = __shfl(t, j);
      float c0 = __shfl(eh[0], j);
      float coef;
      if (H == 1) coef = c0;
      else { float c1 = __shfl(eh[H - 1], j); coef = myhead ? c1 : c0; }
      const float* row = xw + ((size_t)tj * nNodes + sj) * C + lane * VEC;
      if constexpr (VEC == 4) {
        float4 rv = *(const float4*)row;
        acc[0] += coef * rv.x; acc[1] += coef * rv.y;
        acc[2] += coef * rv.z; acc[3] += coef * rv.w;
      } else {
        float2 rv = *(const float2*)row;
        acc[0] += coef * rv.x; acc[1] += coef * rv.y;
      }
    }
  } else {
#pragma unroll
    for (int h = 0; h < H; ++h) m[h] = -1e30f;
    for (int i = start + lane; i < end; i += WAVE) {
      int e = csr[i];
      int s = srcIdx[e];
      int t = etype[e];
#pragma unroll
      for (int h = 0; h < H; ++h) {
        float v = aiv[t][h] + aj[((size_t)t * nNodes + s) * H + h];
        v = v > 0.f ? v : 0.2f * v;
        m[h] = fmaxf(m[h], v);
      }
    }
#pragma unroll
    for (int h = 0; h < H; ++h)
#pragma unroll
      for (int o = 32; o; o >>= 1) m[h] = fmaxf(m[h], __shfl_xor(m[h], o));

    for (int base = start; base < end; base += WAVE) {
      int i = base + lane;
      bool valid = i < end;
      int e = valid ? csr[i] : 0;
      int s = valid ? srcIdx[e] : 0;
      int t = valid ? etype[e] : 0;
      float eh[H];
#pragma unroll
      for (int h = 0; h < H; ++h) {
        float v = aiv[t][h] + aj[((size_t)t * nNodes + s) * H + h];
        v = v > 0.f ? v : 0.2f * v;
        eh[h] = valid ? expf(v - m[h]) : 0.f;
        ssum[h] += eh[h];
      }
      int cnt = end - base; if (cnt > WAVE) cnt = WAVE;
#pragma unroll 4
      for (int j = 0; j < cnt; ++j) {
        int   sj = __shfl(s, j);
        int   tj = __shfl(t, j);
        float c0 = __shfl(eh[0], j);
        float coef;
        if (H == 1) coef = c0;
        else { float c1 = __shfl(eh[H - 1], j); coef = myhead ? c1 : c0; }
        const float* row = xw + ((size_t)tj * nNodes + sj) * C + lane * VEC;
        if constexpr (VEC == 4) {
          float4 rv = *(const float4*)row;
          acc[0] += coef * rv.x; acc[1] += coef * rv.y;
          acc[2] += coef * rv.z; acc[3] += coef * rv.w;
        } else {
          float2 rv = *(const float2*)row;
          acc[0] += coef * rv.x; acc[1] += coef * rv.y;
        }
      }
    }
  }

#pragma unroll
  for (int h = 0; h < H; ++h)
#pragma unroll
    for (int o = 32; o; o >>= 1) ssum[h] += __shfl_xor(ssum[h], o);
  float inv = 1.f / (ssum[myhead] + 1e-16f);

#pragma unroll
  for (int v = 0; v < VEC; ++v) {
    int c = lane * VEC + v;
    float xo = acc[v] * inv + bias[c];
    out[(size_t)node * C + c] = xo > 0.f ? xo : 0.01f * xo;
  }
}

// ---------------- BatchNorm stats ----------------
__global__ void k_bn_stats(const float* __restrict__ h, double* __restrict__ sum,
                           double* __restrict__ sumsq, int nNodes, int C) {
  int col = threadIdx.x;           // blockDim.x == C
  int r0 = blockIdx.x * 256;
  int r1 = r0 + 256; if (r1 > nNodes) r1 = nNodes;
  double s = 0.0, s2 = 0.0;
  for (int r = r0; r < r1; ++r) {
    float v = h[(size_t)r * C + col];
    s += v;
    s2 += (double)v * (double)v;
  }
  atomicAdd(&sum[col], s);
  atomicAdd(&sumsq[col], s2);
}

__global__ void k_bn_finalize(const double* __restrict__ sum,
                              const double* __restrict__ sumsq,
                              const float* __restrict__ g,
                              const float* __restrict__ be,
                              float* __restrict__ scale,
                              float* __restrict__ shift, int nNodes, int C) {
  int c = blockIdx.x * blockDim.x + threadIdx.x;
  if (c >= C) return;
  double mu  = sum[c] / nNodes;
  double var = sumsq[c] / nNodes - mu * mu;
  float rs = (float)(1.0 / sqrt(var + 1e-5));
  float sc = g[c] * rs;
  scale[c] = sc;
  shift[c] = be[c] - (float)mu * sc;
}

// ---------------- head: gather idx rows, fused BN1 apply, sigmoid ---------
__global__ __launch_bounds__(256) void k_head(const float* __restrict__ h,
                                              const int* __restrict__ idx,
                                              const float* __restrict__ scl,
                                              const float* __restrict__ shf,
                                              const float* __restrict__ wm,
                                              const float* __restrict__ bm,
                                              float* __restrict__ outH,
                                              float* __restrict__ outP, int kSel) {
  int wid  = (blockIdx.x * blockDim.x + threadIdx.x) >> 6;
  int lane = threadIdx.x & 63;
  if (wid >= kSel) return;
  int node = idx[wid];
  const float* row = h + (size_t)node * 128;
  int c = lane * 2;
  float2 v = *(const float2*)&row[c];
  v.x = v.x * scl[c + 0] + shf[c + 0];
  v.y = v.y * scl[c + 1] + shf[c + 1];
  *(float2*)&outH[(size_t)wid * 128 + c] = v;
  float p0 = v.x * wm[c * 5 + 0] + v.y * wm[(c + 1) * 5 + 0];
  float p1 = v.x * wm[c * 5 + 1] + v.y * wm[(c + 1) * 5 + 1];
  float p2 = v.x * wm[c * 5 + 2] + v.y * wm[(c + 1) * 5 + 2];
  float p3 = v.x * wm[c * 5 + 3] + v.y * wm[(c + 1) * 5 + 3];
  float p4 = v.x * wm[c * 5 + 4] + v.y * wm[(c + 1) * 5 + 4];
#pragma unroll
  for (int o = 32; o; o >>= 1) {
    p0 += __shfl_xor(p0, o); p1 += __shfl_xor(p1, o); p2 += __shfl_xor(p2, o);
    p3 += __shfl_xor(p3, o); p4 += __shfl_xor(p4, o);
  }
  if (lane == 0) {
    float lg[5] = {p0 + bm[0], p1 + bm[1], p2 + bm[2], p3 + bm[3], p4 + bm[4]};
    float* o = &outP[(size_t)wid * 5];
    o[0] = 1.f / (1.f + expf(-lg[0]));
    o[1] = 1.f / (1.f + expf(-lg[1]));
    o[2] = 1.f / (1.f + expf(-lg[2]));
    o[3] = 1.f / (1.f + expf(-lg[3]));
    o[4] = 1.f / (1.f + expf(-lg[4]));
  }
}

// ---------------------------------------------------------------------------
extern "C" void kernel_launch(void* const* d_in, const int* in_sizes, int n_in,
                              void* d_out, int out_size, void* d_ws, size_t ws_size,
                              hipStream_t stream) {
  const float* x    = (const float*)d_in[0];
  const int*   ei   = (const int*)d_in[1];
  const int*   etyp = (const int*)d_in[2];
  const int*   idx  = (const int*)d_in[3];
  const float* w0   = (const float*)d_in[4];
  const float* q0   = (const float*)d_in[5];
  const float* k0   = (const float*)d_in[6];
  const float* b0   = (const float*)d_in[7];
  const float* g0   = (const float*)d_in[8];
  const float* be0  = (const float*)d_in[9];
  const float* w1   = (const float*)d_in[10];
  const float* q1   = (const float*)d_in[11];
  const float* k1   = (const float*)d_in[12];
  const float* b1   = (const float*)d_in[13];
  const float* g1   = (const float*)d_in[14];
  const float* be1  = (const float*)d_in[15];
  const float* wm   = (const float*)d_in[16];
  const float* bm   = (const float*)d_in[17];

  const int N    = in_sizes[0] / 128;   // 50000
  const int E    = in_sizes[1] / 2;     // 800000
  const int kSel = in_sizes[3];         // 4096
  const int* srcIdx = ei;
  const int* dstIdx = ei + E;

  // ---- workspace carve (256B aligned) ----
  size_t off = 0;
  auto carve = [&](size_t bytes) -> void* {
    off = (off + 255) & ~(size_t)255;
    void* p = (char*)d_ws + off;
    off += bytes;
    return p;
  };
  int*    deg     = (int*)carve((size_t)N * 4);
  int*    rowptr  = (int*)carve((size_t)(N + 1) * 4);
  int*    cursor  = (int*)carve((size_t)N * 4);
  int*    csr     = (int*)carve((size_t)E * 4);
  float*  xw      = (float*)carve((size_t)2 * N * 256 * 4);  // reused layer1
  float*  ai      = (float*)carve((size_t)2 * N * 2 * 4);
  float*  aj      = (float*)carve((size_t)2 * N * 2 * 4);
  float*  h0      = (float*)carve((size_t)N * 256 * 4);
  float*  h1      = (float*)carve((size_t)N * 128 * 4);
  double* dsum    = (double*)carve(256 * 8);
  double* dsumsq  = (double*)carve(256 * 8);
  float*  scl     = (float*)carve(256 * 4);
  float*  shf     = (float*)carve(256 * 4);

  float* outH = (float*)d_out;
  float* outP = outH + (size_t)kSel * 128;

  const int eb = (E + 255) / 256;

  // ---- CSR build ----
  hipMemsetAsync(deg, 0, (size_t)N * 4, stream);
  k_hist<<<eb, 256, 0, stream>>>(dstIdx, deg, E);
  k_scan<<<1, 256, 0, stream>>>(deg, rowptr, cursor, N);
  k_scatter<<<eb, 256, 0, stream>>>(dstIdx, cursor, csr, E);

  // ---- layer 0 ----
  hipMemsetAsync(ai, 0, (size_t)2 * N * 2 * 4, stream);
  hipMemsetAsync(aj, 0, (size_t)2 * N * 2 * 4, stream);
  {
    dim3 grid(256 / 64, (N + 63) / 64, 2);
    k_gemm_attn<2><<<grid, 256, 0, stream>>>(x, w0, xw, nullptr, nullptr,
                                             q0, k0, ai, aj, N, 128, 256);
  }
  k_agg<256, 2><<<(N * WAVE + 255) / 256, 256, 0, stream>>>(
      rowptr, csr, srcIdx, etyp, ai, aj, xw, b0, h0, N);
  hipMemsetAsync(dsum, 0, 256 * 8, stream);
  hipMemsetAsync(dsumsq, 0, 256 * 8, stream);
  k_bn_stats<<<(N + 255) / 256, 256, 0, stream>>>(h0, dsum, dsumsq, N, 256);
  k_bn_finalize<<<1, 256, 0, stream>>>(dsum, dsumsq, g0, be0, scl, shf, N, 256);

  // ---- layer 1 (BN0 apply fused into GEMM A-read) ----
  hipMemsetAsync(ai, 0, (size_t)2 * N * 4, stream);
  hipMemsetAsync(aj, 0, (size_t)2 * N * 4, stream);
  {
    dim3 grid(128 / 64, (N + 63) / 64, 2);
    k_gemm_attn<1><<<grid, 256, 0, stream>>>(h0, w1, xw, scl, shf,
                                             q1, k1, ai, aj, N, 256, 128);
  }
  k_agg<128, 1><<<(N * WAVE + 255) / 256, 256, 0, stream>>>(
      rowptr, csr, srcIdx, etyp, ai, aj, xw, b1, h1, N);
  hipMemsetAsync(dsum, 0, 128 * 8, stream);
  hipMemsetAsync(dsumsq, 0, 128 * 8, stream);
  k_bn_stats<<<(N + 255) / 256, 128, 0, stream>>>(h1, dsum, dsumsq, N, 128);
  k_bn_finalize<<<1, 128, 0, stream>>>(dsum, dsumsq, g1, be1, scl, shf, N, 128);

  // ---- head (BN1 apply fused) ----
  k_head<<<(kSel * WAVE + 255) / 256, 256, 0, stream>>>(
      h1, idx, scl, shf, wm, bm, outH, outP, kSel);
}

// Round 4
// 802.343 us; speedup vs baseline: 1.4942x; 1.1262x over previous
//
#include <hip/hip_runtime.h>
#include <hip/hip_bf16.h>
#include <math.h>

// ---------------------------------------------------------------------------
// RGAT (2 relations) x2 + BatchNorm + head.
//   1. CSR-by-dst (hist -> scan(+cursor) -> scatter)
//   2. split A (fp32 -> bf16 hi/lo, BN-apply fused for layer 1)
//      W pre-transposed+split to [R,N,K] bf16 hi/lo
//   3. xw[r] = A @ W[r] via bf16x3 MFMA (16x16x32), output fp16
//   4. logits ai = xw.q, aj = xw.k  (4 lanes/row)
//   5. per-dst aggregation: register softmax coefs, shfl-broadcast fp16 gather
//   6. BN stats -> finalize; apply fused into consumer (split1 / head)
// ---------------------------------------------------------------------------

#define WAVE 64

typedef short     s16x8 __attribute__((ext_vector_type(8)));
typedef float     f32x4 __attribute__((ext_vector_type(4)));
typedef _Float16  f16x8 __attribute__((ext_vector_type(8)));
typedef _Float16  f16x4 __attribute__((ext_vector_type(4)));
typedef _Float16  f16x2 __attribute__((ext_vector_type(2)));

// round-to-nearest-even fp32 -> bf16 bits
__device__ inline ushort bf_rne(float x) {
  uint u = __float_as_uint(x);
  return (ushort)((u + 0x7FFFu + ((u >> 16) & 1u)) >> 16);
}
__device__ inline ushort bf_hi_resid(float x, float& resid) {
  uint u = __float_as_uint(x);
  uint r = (u + 0x7FFFu + ((u >> 16) & 1u)) & 0xFFFF0000u;
  resid = x - __uint_as_float(r);
  return (ushort)(r >> 16);
}

// ---------------- CSR build ----------------
__global__ __launch_bounds__(256) void k_hist(const int* __restrict__ dst,
                                              int* __restrict__ deg, int E) {
  int e = blockIdx.x * blockDim.x + threadIdx.x;
  if (e < E) atomicAdd(&deg[dst[e]], 1);
}

__global__ __launch_bounds__(256) void k_scan(const int* __restrict__ deg,
                                              int* __restrict__ rowptr,
                                              int* __restrict__ cursor, int n) {
  __shared__ int lsum[256];
  int t = threadIdx.x;
  int chunk = (n + 255) >> 8;
  int s0 = t * chunk;
  int s1 = s0 + chunk; if (s1 > n) s1 = n; if (s0 > n) s0 = n;
  int acc = 0;
  for (int i = s0; i < s1; ++i) acc += deg[i];
  lsum[t] = acc;
  __syncthreads();
  for (int o = 1; o < 256; o <<= 1) {
    int v = 0;
    if (t >= o) v = lsum[t - o];
    __syncthreads();
    if (t >= o) lsum[t] += v;
    __syncthreads();
  }
  int run = (t > 0) ? lsum[t - 1] : 0;
  for (int i = s0; i < s1; ++i) {
    rowptr[i] = run;
    cursor[i] = run;
    run += deg[i];
  }
  if (t == 255) rowptr[n] = lsum[255];
}

__global__ __launch_bounds__(256) void k_scatter(const int* __restrict__ dst,
                                                 int* __restrict__ cursor,
                                                 int* __restrict__ csr, int E) {
  int e = blockIdx.x * blockDim.x + threadIdx.x;
  if (e < E) {
    int p = atomicAdd(&cursor[dst[e]], 1);
    csr[p] = e;
  }
}

// ---------------- fp32 -> bf16 hi/lo split (optional per-col scale/shift) ----
__global__ __launch_bounds__(256) void k_split(const float* __restrict__ in,
                                               ushort* __restrict__ hi,
                                               ushort* __restrict__ lo,
                                               const float* __restrict__ scale,
                                               const float* __restrict__ shift,
                                               int n4, int Cmask) {
  int i = blockIdx.x * blockDim.x + threadIdx.x;
  if (i >= n4) return;
  float4 v = ((const float4*)in)[i];
  if (scale) {
    int c = (i * 4) & Cmask;
    v.x = v.x * scale[c + 0] + shift[c + 0];
    v.y = v.y * scale[c + 1] + shift[c + 1];
    v.z = v.z * scale[c + 2] + shift[c + 2];
    v.w = v.w * scale[c + 3] + shift[c + 3];
  }
  float r0, r1, r2, r3;
  ushort4 hv, lv;
  hv.x = bf_hi_resid(v.x, r0); lv.x = bf_rne(r0);
  hv.y = bf_hi_resid(v.y, r1); lv.y = bf_rne(r1);
  hv.z = bf_hi_resid(v.z, r2); lv.z = bf_rne(r2);
  hv.w = bf_hi_resid(v.w, r3); lv.w = bf_rne(r3);
  ((ushort4*)hi)[i] = hv;
  ((ushort4*)lo)[i] = lv;
}

// ---------------- W: fp32 [R,K,N] -> transposed bf16 hi/lo [R,N,K] ----------
__global__ __launch_bounds__(256) void k_convW(const float* __restrict__ w,
                                               ushort* __restrict__ thi,
                                               ushort* __restrict__ tlo,
                                               int R, int K, int N) {
  int i = blockIdx.x * blockDim.x + threadIdx.x;
  if (i >= R * K * N) return;
  int n  = i % N;
  int t  = i / N;
  int kk = t % K;
  int r  = t / K;
  float x = w[i];
  float resid;
  ushort h = bf_hi_resid(x, resid);
  size_t o = ((size_t)r * N + n) * K + kk;
  thi[o] = h;
  tlo[o] = bf_rne(resid);
}

// ---------------- bf16x3 MFMA GEMM: C[r] = A @ B[r], fp16 out -------------
// Ahi/Alo: [M,K] bf16 bits. Bhi/Blo: [R,N,K] bf16 bits (pre-transposed).
// C: [R,M,N] fp16. BM=BN=128, BK=32, 4 waves (each 64x64 = 4x4 frags).
__global__ __launch_bounds__(256) void k_gemm_mfma(
    const ushort* __restrict__ Ahi, const ushort* __restrict__ Alo,
    const ushort* __restrict__ Bhi, const ushort* __restrict__ Blo,
    _Float16* __restrict__ C, int M, int K, int N) {
  const int r  = blockIdx.z;
  const int n0 = blockIdx.x * 128;
  const int m0 = blockIdx.y * 128;
  __shared__ __align__(16) ushort Ah[128][40];
  __shared__ __align__(16) ushort Al[128][40];
  __shared__ __align__(16) ushort Bh[128][40];
  __shared__ __align__(16) ushort Bl[128][40];
  const int tid  = threadIdx.x;
  const int lane = tid & 63;
  const int wid  = tid >> 6;
  const int wr = wid >> 1, wc = wid & 1;
  const int lr = lane & 15;
  const int lk = (lane >> 4) * 8;
  const size_t bbase = (size_t)r * N * K;

  f32x4 acc[4][4];
#pragma unroll
  for (int i = 0; i < 4; ++i)
#pragma unroll
    for (int j = 0; j < 4; ++j) acc[i][j] = (f32x4){0.f, 0.f, 0.f, 0.f};

  for (int k0 = 0; k0 < K; k0 += 32) {
    // stage A (128 rows x 32 k), hi+lo
#pragma unroll
    for (int rep = 0; rep < 2; ++rep) {
      int idx = tid + rep * 256;
      int row = idx >> 2, piece = idx & 3;
      int gm = m0 + row;
      s16x8 vh = (s16x8)0, vl = (s16x8)0;
      if (gm < M) {
        size_t ga = (size_t)gm * K + k0 + piece * 8;
        vh = *(const s16x8*)(Ahi + ga);
        vl = *(const s16x8*)(Alo + ga);
      }
      *(s16x8*)&Ah[row][piece * 8] = vh;
      *(s16x8*)&Al[row][piece * 8] = vl;
    }
    // stage B (128 cols x 32 k), hi+lo (N is a multiple of 128 -> no guard)
#pragma unroll
    for (int rep = 0; rep < 2; ++rep) {
      int idx = tid + rep * 256;
      int col = idx >> 2, piece = idx & 3;
      size_t ga = bbase + (size_t)(n0 + col) * K + k0 + piece * 8;
      *(s16x8*)&Bh[col][piece * 8] = *(const s16x8*)(Bhi + ga);
      *(s16x8*)&Bl[col][piece * 8] = *(const s16x8*)(Blo + ga);
    }
    __syncthreads();

    s16x8 ah[4], al[4], bh[4], bl[4];
#pragma unroll
    for (int f = 0; f < 4; ++f) {
      ah[f] = *(const s16x8*)&Ah[wr * 64 + f * 16 + lr][lk];
      al[f] = *(const s16x8*)&Al[wr * 64 + f * 16 + lr][lk];
      bh[f] = *(const s16x8*)&Bh[wc * 64 + f * 16 + lr][lk];
      bl[f] = *(const s16x8*)&Bl[wc * 64 + f * 16 + lr][lk];
    }
#pragma unroll
    for (int fi = 0; fi < 4; ++fi)
#pragma unroll
      for (int fj = 0; fj < 4; ++fj) {
        acc[fi][fj] = __builtin_amdgcn_mfma_f32_16x16x32_bf16(
            ah[fi], bh[fj], acc[fi][fj], 0, 0, 0);
        acc[fi][fj] = __builtin_amdgcn_mfma_f32_16x16x32_bf16(
            ah[fi], bl[fj], acc[fi][fj], 0, 0, 0);
        acc[fi][fj] = __builtin_amdgcn_mfma_f32_16x16x32_bf16(
            al[fi], bh[fj], acc[fi][fj], 0, 0, 0);
      }
    __syncthreads();
  }

  // epilogue: fp16 store. D frag: row=(lane>>4)*4+v, col=lane&15
  _Float16* Cr = C + (size_t)r * M * N;
#pragma unroll
  for (int fi = 0; fi < 4; ++fi) {
#pragma unroll
    for (int v = 0; v < 4; ++v) {
      int row = m0 + wr * 64 + fi * 16 + (lane >> 4) * 4 + v;
      if (row < M) {
        size_t rb = (size_t)row * N + n0 + wc * 64 + lr;
#pragma unroll
        for (int fj = 0; fj < 4; ++fj)
          Cr[rb + fj * 16] = (_Float16)acc[fi][fj][v];
      }
    }
  }
}

// ---------------- attention logits from fp16 xw: 4 lanes per row ----------
template <int C, int H>
__global__ __launch_bounds__(256) void k_logits(const _Float16* __restrict__ xw,
                                                const float* __restrict__ qm,
                                                const float* __restrict__ km,
                                                float* __restrict__ ai,
                                                float* __restrict__ aj,
                                                int totalRows) {
  int g = blockIdx.x * blockDim.x + threadIdx.x;
  int row = g >> 2, q4 = g & 3;
  if (row >= totalRows) return;
  constexpr int QC = C / 4;
  const _Float16* rp = xw + (size_t)row * C + q4 * QC;
  float pq[H] = {}, pk[H] = {};
  for (int b = 0; b < QC; b += 8) {
    f16x8 v = *(const f16x8*)(rp + b);
#pragma unroll
    for (int e = 0; e < 8; ++e) {
      float f = (float)v[e];
      int c = q4 * QC + b + e;
#pragma unroll
      for (int h = 0; h < H; ++h) {
        pq[h] += f * qm[c * H + h];
        pk[h] += f * km[c * H + h];
      }
    }
  }
#pragma unroll
  for (int h = 0; h < H; ++h) {
    pq[h] += __shfl_xor(pq[h], 1); pq[h] += __shfl_xor(pq[h], 2);
    pk[h] += __shfl_xor(pk[h], 1); pk[h] += __shfl_xor(pk[h], 2);
  }
  if (q4 == 0) {
#pragma unroll
    for (int h = 0; h < H; ++h) {
      ai[(size_t)row * H + h] = pq[h];
      aj[(size_t)row * H + h] = pk[h];
    }
  }
}

// ---------------- per-dst aggregation (fp16 rows) ----------
template <int C, int H>
__global__ __launch_bounds__(256) void k_agg(const int* __restrict__ rowptr,
                                             const int* __restrict__ csr,
                                             const int* __restrict__ srcIdx,
                                             const int* __restrict__ etype,
                                             const float* __restrict__ ai,
                                             const float* __restrict__ aj,
                                             const _Float16* __restrict__ xw,
                                             const float* __restrict__ bias,
                                             float* __restrict__ out, int nNodes) {
  constexpr int VEC = C / WAVE;   // 4 (L0) or 2 (L1)
  constexpr int OC  = C / H;      // channels per head
  int wid  = (blockIdx.x * blockDim.x + threadIdx.x) >> 6;
  int lane = threadIdx.x & 63;
  if (wid >= nNodes) return;
  const int node  = wid;
  const int start = rowptr[node];
  const int end   = rowptr[node + 1];
  const int deg   = end - start;
  const int myhead = (lane * VEC) / OC;   // 0..H-1

  float aiv[2][H];
#pragma unroll
  for (int rr = 0; rr < 2; ++rr)
#pragma unroll
    for (int h = 0; h < H; ++h)
      aiv[rr][h] = ai[((size_t)rr * nNodes + node) * H + h];

  float acc[VEC] = {};
  float ssum[H] = {};
  float m[H];

  if (deg <= WAVE) {
    int i = start + lane;
    bool valid = i < end;
    int e = valid ? csr[i] : 0;
    int s = valid ? srcIdx[e] : 0;
    int t = valid ? etype[e] : 0;
    float a[H], eh[H];
#pragma unroll
    for (int h = 0; h < H; ++h) {
      float v = aiv[t][h] + aj[((size_t)t * nNodes + s) * H + h];
      v = v > 0.f ? v : 0.2f * v;
      a[h] = valid ? v : -1e30f;
      m[h] = a[h];
    }
#pragma unroll
    for (int h = 0; h < H; ++h)
#pragma unroll
      for (int o = 32; o; o >>= 1) m[h] = fmaxf(m[h], __shfl_xor(m[h], o));
#pragma unroll
    for (int h = 0; h < H; ++h) {
      eh[h] = valid ? expf(a[h] - m[h]) : 0.f;
      ssum[h] = eh[h];
    }
#pragma unroll 4
    for (int j = 0; j < deg; ++j) {
      int   sj = __shfl(s, j);
      int   tj = __shfl(t, j);
      float c0 = __shfl(eh[0], j);
      float coef;
      if (H == 1) coef = c0;
      else { float c1 = __shfl(eh[H - 1], j); coef = myhead ? c1 : c0; }
      const _Float16* row = xw + ((size_t)tj * nNodes + sj) * C + lane * VEC;
      if constexpr (VEC == 4) {
        f16x4 rv = *(const f16x4*)row;
        acc[0] += coef * (float)rv[0]; acc[1] += coef * (float)rv[1];
        acc[2] += coef * (float)rv[2]; acc[3] += coef * (float)rv[3];
      } else {
        f16x2 rv = *(const f16x2*)row;
        acc[0] += coef * (float)rv[0]; acc[1] += coef * (float)rv[1];
      }
    }
  } else {
#pragma unroll
    for (int h = 0; h < H; ++h) m[h] = -1e30f;
    for (int i = start + lane; i < end; i += WAVE) {
      int e = csr[i];
      int s = srcIdx[e];
      int t = etype[e];
#pragma unroll
      for (int h = 0; h < H; ++h) {
        float v = aiv[t][h] + aj[((size_t)t * nNodes + s) * H + h];
        v = v > 0.f ? v : 0.2f * v;
        m[h] = fmaxf(m[h], v);
      }
    }
#pragma unroll
    for (int h = 0; h < H; ++h)
#pragma unroll
      for (int o = 32; o; o >>= 1) m[h] = fmaxf(m[h], __shfl_xor(m[h], o));

    for (int base = start; base < end; base += WAVE) {
      int i = base + lane;
      bool valid = i < end;
      int e = valid ? csr[i] : 0;
      int s = valid ? srcIdx[e] : 0;
      int t = valid ? etype[e] : 0;
      float eh[H];
#pragma unroll
      for (int h = 0; h < H; ++h) {
        float v = aiv[t][h] + aj[((size_t)t * nNodes + s) * H + h];
        v = v > 0.f ? v : 0.2f * v;
        eh[h] = valid ? expf(v - m[h]) : 0.f;
        ssum[h] += eh[h];
      }
      int cnt = end - base; if (cnt > WAVE) cnt = WAVE;
#pragma unroll 4
      for (int j = 0; j < cnt; ++j) {
        int   sj = __shfl(s, j);
        int   tj = __shfl(t, j);
        float c0 = __shfl(eh[0], j);
        float coef;
        if (H == 1) coef = c0;
        else { float c1 = __shfl(eh[H - 1], j); coef = myhead ? c1 : c0; }
        const _Float16* row = xw + ((size_t)tj * nNodes + sj) * C + lane * VEC;
        if constexpr (VEC == 4) {
          f16x4 rv = *(const f16x4*)row;
          acc[0] += coef * (float)rv[0]; acc[1] += coef * (float)rv[1];
          acc[2] += coef * (float)rv[2]; acc[3] += coef * (float)rv[3];
        } else {
          f16x2 rv = *(const f16x2*)row;
          acc[0] += coef * (float)rv[0]; acc[1] += coef * (float)rv[1];
        }
      }
    }
  }

#pragma unroll
  for (int h = 0; h < H; ++h)
#pragma unroll
    for (int o = 32; o; o >>= 1) ssum[h] += __shfl_xor(ssum[h], o);
  float inv = 1.f / (ssum[myhead] + 1e-16f);

#pragma unroll
  for (int v = 0; v < VEC; ++v) {
    int c = lane * VEC + v;
    float xo = acc[v] * inv + bias[c];
    out[(size_t)node * C + c] = xo > 0.f ? xo : 0.01f * xo;
  }
}

// ---------------- BatchNorm stats ----------------
__global__ void k_bn_stats(const float* __restrict__ h, double* __restrict__ sum,
                           double* __restrict__ sumsq, int nNodes, int C) {
  int col = threadIdx.x;           // blockDim.x == C
  int r0 = blockIdx.x * 256;
  int r1 = r0 + 256; if (r1 > nNodes) r1 = nNodes;
  double s = 0.0, s2 = 0.0;
  for (int r = r0; r < r1; ++r) {
    float v = h[(size_t)r * C + col];
    s += v;
    s2 += (double)v * (double)v;
  }
  atomicAdd(&sum[col], s);
  atomicAdd(&sumsq[col], s2);
}

__global__ void k_bn_finalize(const double* __restrict__ sum,
                              const double* __restrict__ sumsq,
                              const float* __restrict__ g,
                              const float* __restrict__ be,
                              float* __restrict__ scale,
                              float* __restrict__ shift, int nNodes, int C) {
  int c = blockIdx.x * blockDim.x + threadIdx.x;
  if (c >= C) return;
  double mu  = sum[c] / nNodes;
  double var = sumsq[c] / nNodes - mu * mu;
  float rs = (float)(1.0 / sqrt(var + 1e-5));
  float sc = g[c] * rs;
  scale[c] = sc;
  shift[c] = be[c] - (float)mu * sc;
}

// ---------------- head: gather idx rows, fused BN1 apply, sigmoid ---------
__global__ __launch_bounds__(256) void k_head(const float* __restrict__ h,
                                              const int* __restrict__ idx,
                                              const float* __restrict__ scl,
                                              const float* __restrict__ shf,
                                              const float* __restrict__ wm,
                                              const float* __restrict__ bm,
                                              float* __restrict__ outH,
                                              float* __restrict__ outP, int kSel) {
  int wid  = (blockIdx.x * blockDim.x + threadIdx.x) >> 6;
  int lane = threadIdx.x & 63;
  if (wid >= kSel) return;
  int node = idx[wid];
  const float* row = h + (size_t)node * 128;
  int c = lane * 2;
  float2 v = *(const float2*)&row[c];
  v.x = v.x * scl[c + 0] + shf[c + 0];
  v.y = v.y * scl[c + 1] + shf[c + 1];
  *(float2*)&outH[(size_t)wid * 128 + c] = v;
  float p0 = v.x * wm[c * 5 + 0] + v.y * wm[(c + 1) * 5 + 0];
  float p1 = v.x * wm[c * 5 + 1] + v.y * wm[(c + 1) * 5 + 1];
  float p2 = v.x * wm[c * 5 + 2] + v.y * wm[(c + 1) * 5 + 2];
  float p3 = v.x * wm[c * 5 + 3] + v.y * wm[(c + 1) * 5 + 3];
  float p4 = v.x * wm[c * 5 + 4] + v.y * wm[(c + 1) * 5 + 4];
#pragma unroll
  for (int o = 32; o; o >>= 1) {
    p0 += __shfl_xor(p0, o); p1 += __shfl_xor(p1, o); p2 += __shfl_xor(p2, o);
    p3 += __shfl_xor(p3, o); p4 += __shfl_xor(p4, o);
  }
  if (lane == 0) {
    float lg[5] = {p0 + bm[0], p1 + bm[1], p2 + bm[2], p3 + bm[3], p4 + bm[4]};
    float* o = &outP[(size_t)wid * 5];
    o[0] = 1.f / (1.f + expf(-lg[0]));
    o[1] = 1.f / (1.f + expf(-lg[1]));
    o[2] = 1.f / (1.f + expf(-lg[2]));
    o[3] = 1.f / (1.f + expf(-lg[3]));
    o[4] = 1.f / (1.f + expf(-lg[4]));
  }
}

// ---------------------------------------------------------------------------
extern "C" void kernel_launch(void* const* d_in, const int* in_sizes, int n_in,
                              void* d_out, int out_size, void* d_ws, size_t ws_size,
                              hipStream_t stream) {
  const float* x    = (const float*)d_in[0];
  const int*   ei   = (const int*)d_in[1];
  const int*   etyp = (const int*)d_in[2];
  const int*   idx  = (const int*)d_in[3];
  const float* w0   = (const float*)d_in[4];
  const float* q0   = (const float*)d_in[5];
  const float* k0   = (const float*)d_in[6];
  const float* b0   = (const float*)d_in[7];
  const float* g0   = (const float*)d_in[8];
  const float* be0  = (const float*)d_in[9];
  const float* w1   = (const float*)d_in[10];
  const float* q1   = (const float*)d_in[11];
  const float* k1   = (const float*)d_in[12];
  const float* b1   = (const float*)d_in[13];
  const float* g1   = (const float*)d_in[14];
  const float* be1  = (const float*)d_in[15];
  const float* wm   = (const float*)d_in[16];
  const float* bm   = (const float*)d_in[17];

  const int N    = in_sizes[0] / 128;   // 50000
  const int E    = in_sizes[1] / 2;     // 800000
  const int kSel = in_sizes[3];         // 4096
  const int* srcIdx = ei;
  const int* dstIdx = ei + E;

  // ---- workspace carve (256B aligned) ----
  size_t off = 0;
  auto carve = [&](size_t bytes) -> void* {
    off = (off + 255) & ~(size_t)255;
    void* p = (char*)d_ws + off;
    off += bytes;
    return p;
  };
  int*      deg    = (int*)carve((size_t)N * 4);
  int*      rowptr = (int*)carve((size_t)(N + 1) * 4);
  int*      cursor = (int*)carve((size_t)N * 4);
  int*      csr    = (int*)carve((size_t)E * 4);
  _Float16* xwh    = (_Float16*)carve((size_t)2 * N * 256 * 2);
  ushort*   Ahi    = (ushort*)carve((size_t)N * 256 * 2);
  ushort*   Alo    = (ushort*)carve((size_t)N * 256 * 2);
  ushort*   W0thi  = (ushort*)carve((size_t)2 * 256 * 128 * 2);
  ushort*   W0tlo  = (ushort*)carve((size_t)2 * 256 * 128 * 2);
  ushort*   W1thi  = (ushort*)carve((size_t)2 * 256 * 128 * 2);
  ushort*   W1tlo  = (ushort*)carve((size_t)2 * 256 * 128 * 2);
  float*    ai     = (float*)carve((size_t)2 * N * 2 * 4);
  float*    aj     = (float*)carve((size_t)2 * N * 2 * 4);
  float*    h0     = (float*)carve((size_t)N * 256 * 4);
  float*    h1     = (float*)carve((size_t)N * 128 * 4);
  double*   dsum   = (double*)carve(256 * 8);
  double*   dsumsq = (double*)carve(256 * 8);
  float*    scl    = (float*)carve(256 * 4);
  float*    shf    = (float*)carve(256 * 4);

  float* outH = (float*)d_out;
  float* outP = outH + (size_t)kSel * 128;

  const int eb = (E + 255) / 256;

  // ---- CSR build ----
  hipMemsetAsync(deg, 0, (size_t)N * 4, stream);
  k_hist<<<eb, 256, 0, stream>>>(dstIdx, deg, E);
  k_scan<<<1, 256, 0, stream>>>(deg, rowptr, cursor, N);
  k_scatter<<<eb, 256, 0, stream>>>(dstIdx, cursor, csr, E);

  // ---- weight prep ----
  k_convW<<<(2 * 128 * 256 + 255) / 256, 256, 0, stream>>>(w0, W0thi, W0tlo,
                                                           2, 128, 256);
  k_convW<<<(2 * 256 * 128 + 255) / 256, 256, 0, stream>>>(w1, W1thi, W1tlo,
                                                           2, 256, 128);

  // ---- layer 0 ----
  k_split<<<((N * 128 / 4) + 255) / 256, 256, 0, stream>>>(
      x, Ahi, Alo, nullptr, nullptr, N * 128 / 4, 0);
  {
    dim3 grid(256 / 128, (N + 127) / 128, 2);
    k_gemm_mfma<<<grid, 256, 0, stream>>>(Ahi, Alo, W0thi, W0tlo, xwh,
                                          N, 128, 256);
  }
  k_logits<256, 2><<<(2 * N * 4 + 255) / 256, 256, 0, stream>>>(
      xwh, q0, k0, ai, aj, 2 * N);
  k_agg<256, 2><<<(N * WAVE + 255) / 256, 256, 0, stream>>>(
      rowptr, csr, srcIdx, etyp, ai, aj, xwh, b0, h0, N);
  hipMemsetAsync(dsum, 0, 256 * 8, stream);
  hipMemsetAsync(dsumsq, 0, 256 * 8, stream);
  k_bn_stats<<<(N + 255) / 256, 256, 0, stream>>>(h0, dsum, dsumsq, N, 256);
  k_bn_finalize<<<1, 256, 0, stream>>>(dsum, dsumsq, g0, be0, scl, shf, N, 256);

  // ---- layer 1 (BN0 apply fused into split) ----
  k_split<<<((N * 256 / 4) + 255) / 256, 256, 0, stream>>>(
      h0, Ahi, Alo, scl, shf, N * 256 / 4, 255);
  {
    dim3 grid(128 / 128, (N + 127) / 128, 2);
    k_gemm_mfma<<<grid, 256, 0, stream>>>(Ahi, Alo, W1thi, W1tlo, xwh,
                                          N, 256, 128);
  }
  k_logits<128, 1><<<(2 * N * 4 + 255) / 256, 256, 0, stream>>>(
      xwh, q1, k1, ai, aj, 2 * N);
  k_agg<128, 1><<<(N * WAVE + 255) / 256, 256, 0, stream>>>(
      rowptr, csr, srcIdx, etyp, ai, aj, xwh, b1, h1, N);
  hipMemsetAsync(dsum, 0, 128 * 8, stream);
  hipMemsetAsync(dsumsq, 0, 128 * 8, stream);
  k_bn_stats<<<(N + 255) / 256, 128, 0, stream>>>(h1, dsum, dsumsq, N, 128);
  k_bn_finalize<<<1, 128, 0, stream>>>(dsum, dsumsq, g1, be1, scl, shf, N, 128);

  // ---- head (BN1 apply fused) ----
  k_head<<<(kSel * WAVE + 255) / 256, 256, 0, stream>>>(
      h1, idx, scl, shf, wm, bm, outH, outP, kSel);
}

// Round 5
// 680.344 us; speedup vs baseline: 1.7621x; 1.1793x over previous
//
#include <hip/hip_runtime.h>
#include <hip/hip_bf16.h>
#include <math.h>

// ---------------------------------------------------------------------------
// RGAT (2 relations) x2 + BatchNorm + head.
//   1. CSR-by-dst (hist -> 3-phase parallel scan -> scatter)
//   2. split A (fp32 -> bf16 hi/lo, BN-apply fused for layer 1)
//      W pre-transposed+split to [R,N,K] bf16 hi/lo
//   3. xw[r] = A @ W[r] via bf16x3 MFMA (16x16x32), output fp16
//   4. logits ai = xw.q, aj = xw.k  (4 lanes/row)
//   5. per-dst aggregation: register softmax coefs, shfl-broadcast fp16 gather
//   6. BN stats -> finalize; apply fused into consumer (split1 / head)
// ---------------------------------------------------------------------------

#define WAVE 64

typedef short     s16x8 __attribute__((ext_vector_type(8)));
typedef float     f32x4 __attribute__((ext_vector_type(4)));
typedef _Float16  f16x8 __attribute__((ext_vector_type(8)));
typedef _Float16  f16x4 __attribute__((ext_vector_type(4)));
typedef _Float16  f16x2 __attribute__((ext_vector_type(2)));

// round-to-nearest-even fp32 -> bf16 bits
__device__ inline ushort bf_rne(float x) {
  uint u = __float_as_uint(x);
  return (ushort)((u + 0x7FFFu + ((u >> 16) & 1u)) >> 16);
}
__device__ inline ushort bf_hi_resid(float x, float& resid) {
  uint u = __float_as_uint(x);
  uint r = (u + 0x7FFFu + ((u >> 16) & 1u)) & 0xFFFF0000u;
  resid = x - __uint_as_float(r);
  return (ushort)(r >> 16);
}

// ---------------- CSR build ----------------
__global__ __launch_bounds__(256) void k_hist(const int* __restrict__ dst,
                                              int* __restrict__ deg, int E) {
  int e = blockIdx.x * blockDim.x + threadIdx.x;
  if (e < E) atomicAdd(&deg[dst[e]], 1);
}

// phase 1: per-block (256-elem chunk) sums
__global__ __launch_bounds__(256) void k_scan_blk(const int* __restrict__ deg,
                                                  int* __restrict__ bsum, int n) {
  int i = blockIdx.x * 256 + threadIdx.x;
  int v = (i < n) ? deg[i] : 0;
#pragma unroll
  for (int o = 32; o; o >>= 1) v += __shfl_xor(v, o);
  __shared__ int ws[4];
  if ((threadIdx.x & 63) == 0) ws[threadIdx.x >> 6] = v;
  __syncthreads();
  if (threadIdx.x == 0) bsum[blockIdx.x] = ws[0] + ws[1] + ws[2] + ws[3];
}

// phase 2: exclusive scan of block sums (single block, chunked), rowptr[n]=E
__global__ __launch_bounds__(256) void k_scan_top(int* __restrict__ bsum, int nb,
                                                  int* __restrict__ rowptr_n,
                                                  int E) {
  __shared__ int sh[256];
  int t = threadIdx.x;
  int carry = 0;
  for (int base = 0; base < nb; base += 256) {
    int i = base + t;
    int v = (i < nb) ? bsum[i] : 0;
    sh[t] = v;
    __syncthreads();
    for (int o = 1; o < 256; o <<= 1) {
      int u = (t >= o) ? sh[t - o] : 0;
      __syncthreads();
      sh[t] += u;
      __syncthreads();
    }
    if (i < nb) bsum[i] = carry + sh[t] - v;
    int blockTotal = sh[255];
    __syncthreads();
    carry += blockTotal;
  }
  if (t == 0) *rowptr_n = E;
}

// phase 3: per-chunk exclusive scan + block offset -> rowptr, cursor
__global__ __launch_bounds__(256) void k_scan_fin(const int* __restrict__ deg,
                                                  const int* __restrict__ bsum,
                                                  int* __restrict__ rowptr,
                                                  int* __restrict__ cursor, int n) {
  int t = threadIdx.x;
  int i = blockIdx.x * 256 + t;
  int v = (i < n) ? deg[i] : 0;
  __shared__ int sh[256];
  sh[t] = v;
  __syncthreads();
  for (int o = 1; o < 256; o <<= 1) {
    int u = (t >= o) ? sh[t - o] : 0;
    __syncthreads();
    sh[t] += u;
    __syncthreads();
  }
  if (i < n) {
    int ex = bsum[blockIdx.x] + sh[t] - v;
    rowptr[i] = ex;
    cursor[i] = ex;
  }
}

__global__ __launch_bounds__(256) void k_scatter(const int* __restrict__ dst,
                                                 int* __restrict__ cursor,
                                                 int* __restrict__ csr, int E) {
  int e = blockIdx.x * blockDim.x + threadIdx.x;
  if (e < E) {
    int p = atomicAdd(&cursor[dst[e]], 1);
    csr[p] = e;
  }
}

// ---------------- fp32 -> bf16 hi/lo split (optional per-col scale/shift) ----
__global__ __launch_bounds__(256) void k_split(const float* __restrict__ in,
                                               ushort* __restrict__ hi,
                                               ushort* __restrict__ lo,
                                               const float* __restrict__ scale,
                                               const float* __restrict__ shift,
                                               int n4, int Cmask) {
  int i = blockIdx.x * blockDim.x + threadIdx.x;
  if (i >= n4) return;
  float4 v = ((const float4*)in)[i];
  if (scale) {
    int c = (i * 4) & Cmask;
    v.x = v.x * scale[c + 0] + shift[c + 0];
    v.y = v.y * scale[c + 1] + shift[c + 1];
    v.z = v.z * scale[c + 2] + shift[c + 2];
    v.w = v.w * scale[c + 3] + shift[c + 3];
  }
  float r0, r1, r2, r3;
  ushort4 hv, lv;
  hv.x = bf_hi_resid(v.x, r0); lv.x = bf_rne(r0);
  hv.y = bf_hi_resid(v.y, r1); lv.y = bf_rne(r1);
  hv.z = bf_hi_resid(v.z, r2); lv.z = bf_rne(r2);
  hv.w = bf_hi_resid(v.w, r3); lv.w = bf_rne(r3);
  ((ushort4*)hi)[i] = hv;
  ((ushort4*)lo)[i] = lv;
}

// ---------------- W: fp32 [R,K,N] -> transposed bf16 hi/lo [R,N,K] ----------
__global__ __launch_bounds__(256) void k_convW(const float* __restrict__ w,
                                               ushort* __restrict__ thi,
                                               ushort* __restrict__ tlo,
                                               int R, int K, int N) {
  int i = blockIdx.x * blockDim.x + threadIdx.x;
  if (i >= R * K * N) return;
  int n  = i % N;
  int t  = i / N;
  int kk = t % K;
  int r  = t / K;
  float x = w[i];
  float resid;
  ushort h = bf_hi_resid(x, resid);
  size_t o = ((size_t)r * N + n) * K + kk;
  thi[o] = h;
  tlo[o] = bf_rne(resid);
}

// ---------------- bf16x3 MFMA GEMM: C[r] = A @ B[r], fp16 out -------------
// Ahi/Alo: [M,K] bf16 bits. Bhi/Blo: [R,N,K] bf16 bits (pre-transposed).
// C: [R,M,N] fp16. BM=BN=128, BK=32, 4 waves (each 64x64 = 4x4 frags).
__global__ __launch_bounds__(256) void k_gemm_mfma(
    const ushort* __restrict__ Ahi, const ushort* __restrict__ Alo,
    const ushort* __restrict__ Bhi, const ushort* __restrict__ Blo,
    _Float16* __restrict__ C, int M, int K, int N) {
  const int r  = blockIdx.z;
  const int n0 = blockIdx.x * 128;
  const int m0 = blockIdx.y * 128;
  __shared__ __align__(16) ushort Ah[128][40];
  __shared__ __align__(16) ushort Al[128][40];
  __shared__ __align__(16) ushort Bh[128][40];
  __shared__ __align__(16) ushort Bl[128][40];
  const int tid  = threadIdx.x;
  const int lane = tid & 63;
  const int wid  = tid >> 6;
  const int wr = wid >> 1, wc = wid & 1;
  const int lr = lane & 15;
  const int lk = (lane >> 4) * 8;
  const size_t bbase = (size_t)r * N * K;

  f32x4 acc[4][4];
#pragma unroll
  for (int i = 0; i < 4; ++i)
#pragma unroll
    for (int j = 0; j < 4; ++j) acc[i][j] = (f32x4){0.f, 0.f, 0.f, 0.f};

  for (int k0 = 0; k0 < K; k0 += 32) {
    // stage A (128 rows x 32 k), hi+lo
#pragma unroll
    for (int rep = 0; rep < 2; ++rep) {
      int idx = tid + rep * 256;
      int row = idx >> 2, piece = idx & 3;
      int gm = m0 + row;
      s16x8 vh = (s16x8)0, vl = (s16x8)0;
      if (gm < M) {
        size_t ga = (size_t)gm * K + k0 + piece * 8;
        vh = *(const s16x8*)(Ahi + ga);
        vl = *(const s16x8*)(Alo + ga);
      }
      *(s16x8*)&Ah[row][piece * 8] = vh;
      *(s16x8*)&Al[row][piece * 8] = vl;
    }
    // stage B (128 cols x 32 k), hi+lo (N multiple of 128 -> no guard)
#pragma unroll
    for (int rep = 0; rep < 2; ++rep) {
      int idx = tid + rep * 256;
      int col = idx >> 2, piece = idx & 3;
      size_t ga = bbase + (size_t)(n0 + col) * K + k0 + piece * 8;
      *(s16x8*)&Bh[col][piece * 8] = *(const s16x8*)(Bhi + ga);
      *(s16x8*)&Bl[col][piece * 8] = *(const s16x8*)(Blo + ga);
    }
    __syncthreads();

    s16x8 ah[4], al[4], bh[4], bl[4];
#pragma unroll
    for (int f = 0; f < 4; ++f) {
      ah[f] = *(const s16x8*)&Ah[wr * 64 + f * 16 + lr][lk];
      al[f] = *(const s16x8*)&Al[wr * 64 + f * 16 + lr][lk];
      bh[f] = *(const s16x8*)&Bh[wc * 64 + f * 16 + lr][lk];
      bl[f] = *(const s16x8*)&Bl[wc * 64 + f * 16 + lr][lk];
    }
#pragma unroll
    for (int fi = 0; fi < 4; ++fi)
#pragma unroll
      for (int fj = 0; fj < 4; ++fj) {
        acc[fi][fj] = __builtin_amdgcn_mfma_f32_16x16x32_bf16(
            ah[fi], bh[fj], acc[fi][fj], 0, 0, 0);
        acc[fi][fj] = __builtin_amdgcn_mfma_f32_16x16x32_bf16(
            ah[fi], bl[fj], acc[fi][fj], 0, 0, 0);
        acc[fi][fj] = __builtin_amdgcn_mfma_f32_16x16x32_bf16(
            al[fi], bh[fj], acc[fi][fj], 0, 0, 0);
      }
    __syncthreads();
  }

  // epilogue: fp16 store. D frag: row=(lane>>4)*4+v, col=lane&15
  _Float16* Cr = C + (size_t)r * M * N;
#pragma unroll
  for (int fi = 0; fi < 4; ++fi) {
#pragma unroll
    for (int v = 0; v < 4; ++v) {
      int row = m0 + wr * 64 + fi * 16 + (lane >> 4) * 4 + v;
      if (row < M) {
        size_t rb = (size_t)row * N + n0 + wc * 64 + lr;
#pragma unroll
        for (int fj = 0; fj < 4; ++fj)
          Cr[rb + fj * 16] = (_Float16)acc[fi][fj][v];
      }
    }
  }
}

// ---------------- attention logits from fp16 xw: 4 lanes per row ----------
template <int C, int H>
__global__ __launch_bounds__(256) void k_logits(const _Float16* __restrict__ xw,
                                                const float* __restrict__ qm,
                                                const float* __restrict__ km,
                                                float* __restrict__ ai,
                                                float* __restrict__ aj,
                                                int totalRows) {
  int g = blockIdx.x * blockDim.x + threadIdx.x;
  int row = g >> 2, q4 = g & 3;
  if (row >= totalRows) return;
  constexpr int QC = C / 4;
  const _Float16* rp = xw + (size_t)row * C + q4 * QC;
  float pq[H] = {}, pk[H] = {};
  for (int b = 0; b < QC; b += 8) {
    f16x8 v = *(const f16x8*)(rp + b);
#pragma unroll
    for (int e = 0; e < 8; ++e) {
      float f = (float)v[e];
      int c = q4 * QC + b + e;
#pragma unroll
      for (int h = 0; h < H; ++h) {
        pq[h] += f * qm[c * H + h];
        pk[h] += f * km[c * H + h];
      }
    }
  }
#pragma unroll
  for (int h = 0; h < H; ++h) {
    pq[h] += __shfl_xor(pq[h], 1); pq[h] += __shfl_xor(pq[h], 2);
    pk[h] += __shfl_xor(pk[h], 1); pk[h] += __shfl_xor(pk[h], 2);
  }
  if (q4 == 0) {
#pragma unroll
    for (int h = 0; h < H; ++h) {
      ai[(size_t)row * H + h] = pq[h];
      aj[(size_t)row * H + h] = pk[h];
    }
  }
}

// ---------------- per-dst aggregation (fp16 rows) ----------
template <int C, int H>
__global__ __launch_bounds__(256) void k_agg(const int* __restrict__ rowptr,
                                             const int* __restrict__ csr,
                                             const int* __restrict__ srcIdx,
                                             const int* __restrict__ etype,
                                             const float* __restrict__ ai,
                                             const float* __restrict__ aj,
                                             const _Float16* __restrict__ xw,
                                             const float* __restrict__ bias,
                                             float* __restrict__ out, int nNodes) {
  constexpr int VEC = C / WAVE;   // 4 (L0) or 2 (L1)
  constexpr int OC  = C / H;      // channels per head
  int wid  = (blockIdx.x * blockDim.x + threadIdx.x) >> 6;
  int lane = threadIdx.x & 63;
  if (wid >= nNodes) return;
  const int node  = wid;
  const int start = rowptr[node];
  const int end   = rowptr[node + 1];
  const int deg   = end - start;
  const int myhead = (lane * VEC) / OC;   // 0..H-1

  float aiv[2][H];
#pragma unroll
  for (int rr = 0; rr < 2; ++rr)
#pragma unroll
    for (int h = 0; h < H; ++h)
      aiv[rr][h] = ai[((size_t)rr * nNodes + node) * H + h];

  float acc[VEC] = {};
  float ssum[H] = {};
  float m[H];

  if (deg <= WAVE) {
    int i = start + lane;
    bool valid = i < end;
    int e = valid ? csr[i] : 0;
    int s = valid ? srcIdx[e] : 0;
    int t = valid ? etype[e] : 0;
    float a[H], eh[H];
#pragma unroll
    for (int h = 0; h < H; ++h) {
      float v = aiv[t][h] + aj[((size_t)t * nNodes + s) * H + h];
      v = v > 0.f ? v : 0.2f * v;
      a[h] = valid ? v : -1e30f;
      m[h] = a[h];
    }
#pragma unroll
    for (int h = 0; h < H; ++h)
#pragma unroll
      for (int o = 32; o; o >>= 1) m[h] = fmaxf(m[h], __shfl_xor(m[h], o));
#pragma unroll
    for (int h = 0; h < H; ++h) {
      eh[h] = valid ? expf(a[h] - m[h]) : 0.f;
      ssum[h] = eh[h];
    }
#pragma unroll 4
    for (int j = 0; j < deg; ++j) {
      int   sj = __shfl(s, j);
      int   tj = __shfl(t, j);
      float c0 = __shfl(eh[0], j);
      float coef;
      if (H == 1) coef = c0;
      else { float c1 = __shfl(eh[H - 1], j); coef = myhead ? c1 : c0; }
      const _Float16* row = xw + ((size_t)tj * nNodes + sj) * C + lane * VEC;
      if constexpr (VEC == 4) {
        f16x4 rv = *(const f16x4*)row;
        acc[0] += coef * (float)rv[0]; acc[1] += coef * (float)rv[1];
        acc[2] += coef * (float)rv[2]; acc[3] += coef * (float)rv[3];
      } else {
        f16x2 rv = *(const f16x2*)row;
        acc[0] += coef * (float)rv[0]; acc[1] += coef * (float)rv[1];
      }
    }
  } else {
#pragma unroll
    for (int h = 0; h < H; ++h) m[h] = -1e30f;
    for (int i = start + lane; i < end; i += WAVE) {
      int e = csr[i];
      int s = srcIdx[e];
      int t = etype[e];
#pragma unroll
      for (int h = 0; h < H; ++h) {
        float v = aiv[t][h] + aj[((size_t)t * nNodes + s) * H + h];
        v = v > 0.f ? v : 0.2f * v;
        m[h] = fmaxf(m[h], v);
      }
    }
#pragma unroll
    for (int h = 0; h < H; ++h)
#pragma unroll
      for (int o = 32; o; o >>= 1) m[h] = fmaxf(m[h], __shfl_xor(m[h], o));

    for (int base = start; base < end; base += WAVE) {
      int i = base + lane;
      bool valid = i < end;
      int e = valid ? csr[i] : 0;
      int s = valid ? srcIdx[e] : 0;
      int t = valid ? etype[e] : 0;
      float eh[H];
#pragma unroll
      for (int h = 0; h < H; ++h) {
        float v = aiv[t][h] + aj[((size_t)t * nNodes + s) * H + h];
        v = v > 0.f ? v : 0.2f * v;
        eh[h] = valid ? expf(v - m[h]) : 0.f;
        ssum[h] += eh[h];
      }
      int cnt = end - base; if (cnt > WAVE) cnt = WAVE;
#pragma unroll 4
      for (int j = 0; j < cnt; ++j) {
        int   sj = __shfl(s, j);
        int   tj = __shfl(t, j);
        float c0 = __shfl(eh[0], j);
        float coef;
        if (H == 1) coef = c0;
        else { float c1 = __shfl(eh[H - 1], j); coef = myhead ? c1 : c0; }
        const _Float16* row = xw + ((size_t)tj * nNodes + sj) * C + lane * VEC;
        if constexpr (VEC == 4) {
          f16x4 rv = *(const f16x4*)row;
          acc[0] += coef * (float)rv[0]; acc[1] += coef * (float)rv[1];
          acc[2] += coef * (float)rv[2]; acc[3] += coef * (float)rv[3];
        } else {
          f16x2 rv = *(const f16x2*)row;
          acc[0] += coef * (float)rv[0]; acc[1] += coef * (float)rv[1];
        }
      }
    }
  }

#pragma unroll
  for (int h = 0; h < H; ++h)
#pragma unroll
    for (int o = 32; o; o >>= 1) ssum[h] += __shfl_xor(ssum[h], o);
  float inv = 1.f / (ssum[myhead] + 1e-16f);

#pragma unroll
  for (int v = 0; v < VEC; ++v) {
    int c = lane * VEC + v;
    float xo = acc[v] * inv + bias[c];
    out[(size_t)node * C + c] = xo > 0.f ? xo : 0.01f * xo;
  }
}

// ---------------- BatchNorm stats ----------------
__global__ void k_bn_stats(const float* __restrict__ h, double* __restrict__ sum,
                           double* __restrict__ sumsq, int nNodes, int C) {
  int col = threadIdx.x;           // blockDim.x == C
  int r0 = blockIdx.x * 256;
  int r1 = r0 + 256; if (r1 > nNodes) r1 = nNodes;
  double s = 0.0, s2 = 0.0;
  for (int r = r0; r < r1; ++r) {
    float v = h[(size_t)r * C + col];
    s += v;
    s2 += (double)v * (double)v;
  }
  atomicAdd(&sum[col], s);
  atomicAdd(&sumsq[col], s2);
}

__global__ void k_bn_finalize(const double* __restrict__ sum,
                              const double* __restrict__ sumsq,
                              const float* __restrict__ g,
                              const float* __restrict__ be,
                              float* __restrict__ scale,
                              float* __restrict__ shift, int nNodes, int C) {
  int c = blockIdx.x * blockDim.x + threadIdx.x;
  if (c >= C) return;
  double mu  = sum[c] / nNodes;
  double var = sumsq[c] / nNodes - mu * mu;
  float rs = (float)(1.0 / sqrt(var + 1e-5));
  float sc = g[c] * rs;
  scale[c] = sc;
  shift[c] = be[c] - (float)mu * sc;
}

// ---------------- head: gather idx rows, fused BN1 apply, sigmoid ---------
__global__ __launch_bounds__(256) void k_head(const float* __restrict__ h,
                                              const int* __restrict__ idx,
                                              const float* __restrict__ scl,
                                              const float* __restrict__ shf,
                                              const float* __restrict__ wm,
                                              const float* __restrict__ bm,
                                              float* __restrict__ outH,
                                              float* __restrict__ outP, int kSel) {
  int wid  = (blockIdx.x * blockDim.x + threadIdx.x) >> 6;
  int lane = threadIdx.x & 63;
  if (wid >= kSel) return;
  int node = idx[wid];
  const float* row = h + (size_t)node * 128;
  int c = lane * 2;
  float2 v = *(const float2*)&row[c];
  v.x = v.x * scl[c + 0] + shf[c + 0];
  v.y = v.y * scl[c + 1] + shf[c + 1];
  *(float2*)&outH[(size_t)wid * 128 + c] = v;
  float p0 = v.x * wm[c * 5 + 0] + v.y * wm[(c + 1) * 5 + 0];
  float p1 = v.x * wm[c * 5 + 1] + v.y * wm[(c + 1) * 5 + 1];
  float p2 = v.x * wm[c * 5 + 2] + v.y * wm[(c + 1) * 5 + 2];
  float p3 = v.x * wm[c * 5 + 3] + v.y * wm[(c + 1) * 5 + 3];
  float p4 = v.x * wm[c * 5 + 4] + v.y * wm[(c + 1) * 5 + 4];
#pragma unroll
  for (int o = 32; o; o >>= 1) {
    p0 += __shfl_xor(p0, o); p1 += __shfl_xor(p1, o); p2 += __shfl_xor(p2, o);
    p3 += __shfl_xor(p3, o); p4 += __shfl_xor(p4, o);
  }
  if (lane == 0) {
    float lg[5] = {p0 + bm[0], p1 + bm[1], p2 + bm[2], p3 + bm[3], p4 + bm[4]};
    float* o = &outP[(size_t)wid * 5];
    o[0] = 1.f / (1.f + expf(-lg[0]));
    o[1] = 1.f / (1.f + expf(-lg[1]));
    o[2] = 1.f / (1.f + expf(-lg[2]));
    o[3] = 1.f / (1.f + expf(-lg[3]));
    o[4] = 1.f / (1.f + expf(-lg[4]));
  }
}

// ---------------------------------------------------------------------------
extern "C" void kernel_launch(void* const* d_in, const int* in_sizes, int n_in,
                              void* d_out, int out_size, void* d_ws, size_t ws_size,
                              hipStream_t stream) {
  const float* x    = (const float*)d_in[0];
  const int*   ei   = (const int*)d_in[1];
  const int*   etyp = (const int*)d_in[2];
  const int*   idx  = (const int*)d_in[3];
  const float* w0   = (const float*)d_in[4];
  const float* q0   = (const float*)d_in[5];
  const float* k0   = (const float*)d_in[6];
  const float* b0   = (const float*)d_in[7];
  const float* g0   = (const float*)d_in[8];
  const float* be0  = (const float*)d_in[9];
  const float* w1   = (const float*)d_in[10];
  const float* q1   = (const float*)d_in[11];
  const float* k1   = (const float*)d_in[12];
  const float* b1   = (const float*)d_in[13];
  const float* g1   = (const float*)d_in[14];
  const float* be1  = (const float*)d_in[15];
  const float* wm   = (const float*)d_in[16];
  const float* bm   = (const float*)d_in[17];

  const int N    = in_sizes[0] / 128;   // 50000
  const int E    = in_sizes[1] / 2;     // 800000
  const int kSel = in_sizes[3];         // 4096
  const int* srcIdx = ei;
  const int* dstIdx = ei + E;

  // ---- workspace carve (256B aligned) ----
  size_t off = 0;
  auto carve = [&](size_t bytes) -> void* {
    off = (off + 255) & ~(size_t)255;
    void* p = (char*)d_ws + off;
    off += bytes;
    return p;
  };
  int*      deg    = (int*)carve((size_t)N * 4);
  int*      rowptr = (int*)carve((size_t)(N + 1) * 4);
  int*      cursor = (int*)carve((size_t)N * 4);
  int*      bsum   = (int*)carve((size_t)((N + 255) / 256) * 4);
  int*      csr    = (int*)carve((size_t)E * 4);
  _Float16* xwh    = (_Float16*)carve((size_t)2 * N * 256 * 2);
  ushort*   Ahi    = (ushort*)carve((size_t)N * 256 * 2);
  ushort*   Alo    = (ushort*)carve((size_t)N * 256 * 2);
  ushort*   W0thi  = (ushort*)carve((size_t)2 * 256 * 128 * 2);
  ushort*   W0tlo  = (ushort*)carve((size_t)2 * 256 * 128 * 2);
  ushort*   W1thi  = (ushort*)carve((size_t)2 * 256 * 128 * 2);
  ushort*   W1tlo  = (ushort*)carve((size_t)2 * 256 * 128 * 2);
  float*    ai     = (float*)carve((size_t)2 * N * 2 * 4);
  float*    aj     = (float*)carve((size_t)2 * N * 2 * 4);
  float*    h0     = (float*)carve((size_t)N * 256 * 4);
  float*    h1     = (float*)carve((size_t)N * 128 * 4);
  double*   dsum   = (double*)carve(256 * 8);
  double*   dsumsq = (double*)carve(256 * 8);
  float*    scl    = (float*)carve(256 * 4);
  float*    shf    = (float*)carve(256 * 4);

  float* outH = (float*)d_out;
  float* outP = outH + (size_t)kSel * 128;

  const int eb = (E + 255) / 256;
  const int nbBlocks = (N + 255) / 256;

  // ---- CSR build (parallel scan) ----
  hipMemsetAsync(deg, 0, (size_t)N * 4, stream);
  k_hist<<<eb, 256, 0, stream>>>(dstIdx, deg, E);
  k_scan_blk<<<nbBlocks, 256, 0, stream>>>(deg, bsum, N);
  k_scan_top<<<1, 256, 0, stream>>>(bsum, nbBlocks, rowptr + N, E);
  k_scan_fin<<<nbBlocks, 256, 0, stream>>>(deg, bsum, rowptr, cursor, N);
  k_scatter<<<eb, 256, 0, stream>>>(dstIdx, cursor, csr, E);

  // ---- weight prep ----
  k_convW<<<(2 * 128 * 256 + 255) / 256, 256, 0, stream>>>(w0, W0thi, W0tlo,
                                                           2, 128, 256);
  k_convW<<<(2 * 256 * 128 + 255) / 256, 256, 0, stream>>>(w1, W1thi, W1tlo,
                                                           2, 256, 128);

  // ---- layer 0 ----
  k_split<<<((N * 128 / 4) + 255) / 256, 256, 0, stream>>>(
      x, Ahi, Alo, nullptr, nullptr, N * 128 / 4, 0);
  {
    dim3 grid(256 / 128, (N + 127) / 128, 2);
    k_gemm_mfma<<<grid, 256, 0, stream>>>(Ahi, Alo, W0thi, W0tlo, xwh,
                                          N, 128, 256);
  }
  k_logits<256, 2><<<(2 * N * 4 + 255) / 256, 256, 0, stream>>>(
      xwh, q0, k0, ai, aj, 2 * N);
  k_agg<256, 2><<<(N * WAVE + 255) / 256, 256, 0, stream>>>(
      rowptr, csr, srcIdx, etyp, ai, aj, xwh, b0, h0, N);
  hipMemsetAsync(dsum, 0, 256 * 8, stream);
  hipMemsetAsync(dsumsq, 0, 256 * 8, stream);
  k_bn_stats<<<(N + 255) / 256, 256, 0, stream>>>(h0, dsum, dsumsq, N, 256);
  k_bn_finalize<<<1, 256, 0, stream>>>(dsum, dsumsq, g0, be0, scl, shf, N, 256);

  // ---- layer 1 (BN0 apply fused into split) ----
  k_split<<<((N * 256 / 4) + 255) / 256, 256, 0, stream>>>(
      h0, Ahi, Alo, scl, shf, N * 256 / 4, 255);
  {
    dim3 grid(128 / 128, (N + 127) / 128, 2);
    k_gemm_mfma<<<grid, 256, 0, stream>>>(Ahi, Alo, W1thi, W1tlo, xwh,
                                          N, 256, 128);
  }
  k_logits<128, 1><<<(2 * N * 4 + 255) / 256, 256, 0, stream>>>(
      xwh, q1, k1, ai, aj, 2 * N);
  k_agg<128, 1><<<(N * WAVE + 255) / 256, 256, 0, stream>>>(
      rowptr, csr, srcIdx, etyp, ai, aj, xwh, b1, h1, N);
  hipMemsetAsync(dsum, 0, 128 * 8, stream);
  hipMemsetAsync(dsumsq, 0, 128 * 8, stream);
  k_bn_stats<<<(N + 255) / 256, 128, 0, stream>>>(h1, dsum, dsumsq, N, 128);
  k_bn_finalize<<<1, 128, 0, stream>>>(dsum, dsumsq, g1, be1, scl, shf, N, 128);

  // ---- head (BN1 apply fused) ----
  k_head<<<(kSel * WAVE + 255) / 256, 256, 0, stream>>>(
      h1, idx, scl, shf, wm, bm, outH, outP, kSel);
}